// Round 12
// baseline (277.167 us; speedup 1.0000x reference)
//
#include <hip/hip_runtime.h>
#include <hip/hip_bf16.h>
#include <stdint.h>

typedef __attribute__((ext_vector_type(8))) short bf16x8;
typedef __attribute__((ext_vector_type(4))) float f32x4;
typedef __attribute__((ext_vector_type(8))) unsigned short u16x8;
typedef __attribute__((ext_vector_type(4))) unsigned short u16x4;

#define B_ 2
#define S_ 2048
#define E_ 2048
#define H_ 16
#define M_ 2048
#define D_ 128

#define MFMA16(a, b, c) __builtin_amdgcn_mfma_f32_16x16x32_bf16(a, b, c, 0, 0, 0)
#define MFMA8(a, b, c) __builtin_amdgcn_mfma_f32_16x16x32_fp8_fp8(a, b, c, 0, 0, 0)

__device__ inline unsigned short f2bf(float f) {
  union { float f; unsigned u; } v; v.f = f;
  unsigned r = v.u + 0x7FFFu + ((v.u >> 16) & 1u);
  return (unsigned short)(r >> 16);
}
__device__ inline float bf2f(unsigned short h) {
  union { unsigned u; float f; } v; v.u = ((unsigned)h) << 16;
  return v.f;
}

// f32 -> OCP e4m3fn, RNE, saturating. Unbiased (used for K/Q/V encodes).
__device__ inline unsigned char f2e4m3(float f) {
  union { float f; uint32_t u; } v; v.f = f;
  uint32_t sign = (v.u >> 24) & 0x80u;
  uint32_t b = v.u & 0x7FFFFFFFu;
  if (b >= 0x43E00000u) return (unsigned char)(sign | 0x7E);  // >=448 clamp
  int e = (int)(b >> 23) - 127;
  uint32_t man = (b & 0x7FFFFFu) | 0x800000u;  // 24-bit with implicit 1
  if (e < -13) return (unsigned char)sign;     // underflow to 0
  if (e < -6) {
    int ts = 14 - e;  // 21..27
    uint32_t q = man >> ts;
    uint32_t rem = man & ((1u << ts) - 1u);
    uint32_t half = 1u << (ts - 1);
    if (rem > half || (rem == half && (q & 1u))) q++;
    return (unsigned char)(sign | q);          // q==8 -> min normal, correct
  }
  uint32_t q = (b >> 20) & 7u;
  uint32_t rem = b & 0xFFFFFu;
  uint32_t enc = ((uint32_t)(e + 7) << 3) | q;
  if (rem > 0x80000u || (rem == 0x80000u && (enc & 1u))) enc++;
  if (enc >= 0x7Fu) enc = 0x7Eu;
  return (unsigned char)(sign | enc);
}

// native 2^x
__device__ inline float exp2a(float x) {
  float r;
  asm("v_exp_f32 %0, %1" : "=v"(r) : "v"(x));
  return r;
}

__device__ inline void gload_lds16(const void* g, void* l) {
  __builtin_amdgcn_global_load_lds(
      (__attribute__((address_space(1))) void*)g,
      (__attribute__((address_space(3))) void*)l, 16, 0, 0);
}

__device__ inline bf16x8 pack8(float4 f0, float4 f1) {
  bf16x8 o;
  o[0] = (short)f2bf(f0.x); o[1] = (short)f2bf(f0.y);
  o[2] = (short)f2bf(f0.z); o[3] = (short)f2bf(f0.w);
  o[4] = (short)f2bf(f1.x); o[5] = (short)f2bf(f1.y);
  o[6] = (short)f2bf(f1.z); o[7] = (short)f2bf(f1.w);
  return o;
}

__device__ inline float block_sum(float v) {
  __shared__ float red[4];
  #pragma unroll
  for (int o = 32; o > 0; o >>= 1) v += __shfl_xor(v, o);
  int tid = threadIdx.x;
  if ((tid & 63) == 0) red[tid >> 6] = v;
  __syncthreads();
  return red[0] + red[1] + red[2] + red[3];
}

// ---------------- f32 -> bf16 convert (wq) ----------------
__global__ __launch_bounds__(256) void f32_to_bf16_kernel(
    const float* __restrict__ in, unsigned short* __restrict__ out, int n4)
{
  int i = blockIdx.x * 256 + threadIdx.x;
  if (i >= n4) return;
  float4 v = ((const float4*)in)[i];
  u16x4 o;
  o[0] = f2bf(v.x); o[1] = f2bf(v.y); o[2] = f2bf(v.z); o[3] = f2bf(v.w);
  *(u16x4*)(out + (size_t)i * 4) = o;
}

// ---------------- RMSNorm(query) -> bf16 qn ----------------
__global__ __launch_bounds__(256) void rmsnorm_q_kernel(
    const float* __restrict__ x, const float* __restrict__ w,
    unsigned short* __restrict__ y)
{
  const int row = blockIdx.x;
  const int tid = threadIdx.x;
  const float* xr = x + (size_t)row * E_;
  float4 v0 = ((const float4*)xr)[tid * 2];
  float4 v1 = ((const float4*)xr)[tid * 2 + 1];
  float ss = v0.x*v0.x + v0.y*v0.y + v0.z*v0.z + v0.w*v0.w
           + v1.x*v1.x + v1.y*v1.y + v1.z*v1.z + v1.w*v1.w;
  float tot = block_sum(ss);
  float sc = rsqrtf(tot * (1.0f / E_) + 1e-5f);
  float vals[8] = {v0.x, v0.y, v0.z, v0.w, v1.x, v1.y, v1.z, v1.w};
  const float* wr = w + tid * 8;
  u16x8 o;
  #pragma unroll
  for (int j = 0; j < 8; ++j) o[j] = f2bf(vals[j] * sc * wr[j]);
  *(u16x8*)(y + (size_t)row * E_ + tid * 8) = o;
}

// ---------------- GEMM C[M,N] = A[M,K] @ B[N,K]^T (bf16 in, fp8 out) ----------------
__global__ __launch_bounds__(256) void gemm_qproj(
    const unsigned short* __restrict__ A, const unsigned short* __restrict__ B,
    unsigned char* __restrict__ C, int M, int N, int K)
{
  __shared__ __align__(16) unsigned short As[128 * 64];  // 16KB
  __shared__ __align__(16) unsigned short Bs[128 * 64];  // 16KB
  const int nwg = gridDim.x;
  const int cpx = nwg >> 3;
  const int swz = (blockIdx.x & 7) * cpx + (blockIdx.x >> 3);
  const int mt = M >> 7;
  const int bm = (swz % mt) * 128;
  const int bn = (swz / mt) * 128;
  const int tid = threadIdx.x;
  const int wave = tid >> 6, lane = tid & 63;
  const int r = lane & 15, g = lane >> 4;
  const int wm = (wave >> 1) * 64, wn = (wave & 1) * 64;
  const int fx = (r & 7) << 4;

  f32x4 acc[4][4] = {};

  for (int k0 = 0; k0 < K; k0 += 64) {
    #pragma unroll
    for (int c = 0; c < 4; ++c) {
      int chunk = wave * 4 + c;
      int off = chunk * 1024 + lane * 16;
      int row = off >> 7;
      int cb = (off & 127) ^ ((row & 7) << 4);
      gload_lds16((const char*)A + ((size_t)(bm + row) * K + k0) * 2 + cb,
                  (char*)As + chunk * 1024);
      gload_lds16((const char*)B + ((size_t)(bn + row) * K + k0) * 2 + cb,
                  (char*)Bs + chunk * 1024);
    }
    __syncthreads();
    #pragma unroll
    for (int kc = 0; kc < 2; ++kc) {
      bf16x8 a[4], bb[4];
      #pragma unroll
      for (int m = 0; m < 4; ++m)
        a[m] = *(const bf16x8*)((const char*)As + (wm + m * 16 + r) * 128
                                + ((kc * 64 + g * 16) ^ fx));
      #pragma unroll
      for (int n = 0; n < 4; ++n)
        bb[n] = *(const bf16x8*)((const char*)Bs + (wn + n * 16 + r) * 128
                                 + ((kc * 64 + g * 16) ^ fx));
      #pragma unroll
      for (int m = 0; m < 4; ++m)
        #pragma unroll
        for (int n = 0; n < 4; ++n)
          acc[m][n] = MFMA16(a[m], bb[n], acc[m][n]);
    }
    __syncthreads();
  }
  #pragma unroll
  for (int m = 0; m < 4; ++m)
    #pragma unroll
    for (int n = 0; n < 4; ++n)
      #pragma unroll
      for (int i = 0; i < 4; ++i) {
        int row = bm + wm + m * 16 + g * 4 + i;
        int col = bn + wn + n * 16 + r;
        C[(size_t)row * N + col] = f2e4m3(acc[m][n][i]);
      }
}

// ---------------- fused per-head K AND V projections (fp8 out, x32 encode) ----------------
// kout[h][m][d] = e4m3( (sum sp*wk) * 32 );  vt[h][d][m] = e4m3( (sum sp*wv) * 32 )
// (beta/sqrt(D)*log2e applied in f32 inside attn; x32 keeps e4m3 out of denormals)
__global__ __launch_bounds__(256, 1) void proj_kv_kernel(
    const float* __restrict__ sp, const float* __restrict__ wk,
    const float* __restrict__ wv,
    unsigned char* __restrict__ kout, unsigned char* __restrict__ vtout)
{
  const int m0 = blockIdx.x * 128;
  const int h = blockIdx.y;
  const int tid = threadIdx.x, wave = tid >> 6, lane = tid & 63;
  const int r = lane & 15, g = lane >> 4;
  const int wm = (wave >> 1) * 64, wn = (wave & 1) * 64;
  const float* spb = sp + ((size_t)h * M_ + m0) * D_;
  f32x4 acck[4][4] = {};
  f32x4 accv[4][4] = {};
  #pragma unroll
  for (int kc = 0; kc < 4; ++kc) {
    bf16x8 a[4], bk[4], bv[4];
    #pragma unroll
    for (int m = 0; m < 4; ++m) {
      const float* p = spb + (size_t)(wm + m * 16 + r) * D_ + kc * 32 + g * 8;
      a[m] = pack8(*(const float4*)p, *(const float4*)(p + 4));
    }
    #pragma unroll
    for (int n = 0; n < 4; ++n) {
      const float* pk = wk + (size_t)(wn + n * 16 + r) * D_ + kc * 32 + g * 8;
      bk[n] = pack8(*(const float4*)pk, *(const float4*)(pk + 4));
      const float* pv = wv + (size_t)(wn + n * 16 + r) * D_ + kc * 32 + g * 8;
      bv[n] = pack8(*(const float4*)pv, *(const float4*)(pv + 4));
    }
    #pragma unroll
    for (int m = 0; m < 4; ++m)
      #pragma unroll
      for (int n = 0; n < 4; ++n) {
        acck[m][n] = MFMA16(a[m], bk[n], acck[m][n]);
        accv[m][n] = MFMA16(a[m], bv[n], accv[m][n]);
      }
  }
  #pragma unroll
  for (int m = 0; m < 4; ++m)
    #pragma unroll
    for (int n = 0; n < 4; ++n)
      #pragma unroll
      for (int i = 0; i < 4; ++i) {
        kout[((size_t)h * M_ + m0 + wm + m * 16 + g * 4 + i) * D_ + wn + n * 16 + r]
            = f2e4m3(acck[m][n][i] * 32.0f);
        vtout[((size_t)h * D_ + wn + n * 16 + r) * M_ + m0 + wm + m * 16 + g * 4 + i]
            = f2e4m3(accv[m][n][i] * 32.0f);
      }
}

// ---------------- flash attention over memory slots (fp8 K/Q/V/P) ----------------
// grid: (S/128, H, B); block 512 (8 waves x 16 q-rows); KVBLK=128.
// Same byte-layout/swizzle/dbuf structure as the verified bf16 r7 kernel
// (16KB tiles, 128B rows, (row&7)<<4 XOR both sides) but fp8 elements:
// LDS traffic per wave halves (the measured binding resource).
// l computed by an extra MFMA against a ones-fragment -> exact cancellation
// of P's quantization bias, and no epilogue shuffle/transpose needed.
__global__ __launch_bounds__(512, 4) void attn_kernel(
    const unsigned char* __restrict__ q,    // [B*S][E] e4m3 (natural scale)
    const unsigned char* __restrict__ kb,   // [H][M][D] e4m3 (x32)
    const unsigned char* __restrict__ vtb,  // [H][D][M] e4m3 (x32)
    const float* __restrict__ beta,
    unsigned short* __restrict__ ret)       // [B*S][E] bf16
{
  __shared__ __align__(16) unsigned char Ks[2][128 * 128];  // 2 x 16KB
  __shared__ __align__(16) unsigned char Vs[2][128 * 128];  // 2 x 16KB
  __shared__ __align__(16) unsigned char Ps[8][16 * 128];   // 16KB
  const int s0 = blockIdx.x * 128;
  const int h = blockIdx.y;
  const int b = blockIdx.z;
  const int tid = threadIdx.x, wave = tid >> 6, lane = tid & 63;
  const int r = lane & 15, g = lane >> 4;
  const int fx = (r & 7) << 4;
  // s_true*log2e*beta/sqrt(D) = s_f32 * escale  (k was encoded x32)
  const float escale = beta[h] * (0.08838834764831845f * 1.4426950408889634f / 32.0f);

  // Q fragment: 16 rows per wave (q-row = wave*16 + r), 8 bytes per kc
  long long qf[4];
  {
    const unsigned char* qr0 =
        q + ((size_t)(b * S_) + s0 + wave * 16 + r) * E_ + h * D_;
    #pragma unroll
    for (int kc = 0; kc < 4; ++kc)
      qf[kc] = *(const long long*)(qr0 + kc * 32 + g * 8);
  }

  const unsigned char* Kh = kb + (size_t)h * M_ * D_;
  const unsigned char* Vh = vtb + (size_t)h * D_ * M_;
  unsigned char* Pw = Ps[wave];
  const long long ONES = 0x3838383838383838LL;  // e4m3 1.0 x8

  f32x4 o[8] = {};
  f32x4 ol = {};

  auto stage = [&](int buf, int m0) {
    #pragma unroll
    for (int c = 0; c < 2; ++c) {
      int chunk = wave * 2 + c;           // 16 x 1KB chunks per 16KB tile
      int off = chunk * 1024 + lane * 16;
      int row = off >> 7;                 // 128B rows
      int cb = (off & 127) ^ ((row & 7) << 4);
      gload_lds16(Kh + (size_t)(m0 + row) * 128 + cb, (char*)Ks[buf] + chunk * 1024);
      gload_lds16(Vh + (size_t)row * M_ + m0 + cb, (char*)Vs[buf] + chunk * 1024);
    }
  };

  stage(0, 0);
  __syncthreads();

  int cur = 0;
  for (int t = 0; t < M_ / 128; ++t) {
    if (t + 1 < M_ / 128) stage(cur ^ 1, (t + 1) * 128);

    const unsigned char* Kc = Ks[cur];
    const unsigned char* Vc = Vs[cur];

    // ---- S^T = K @ Q^T : lane (r,g) gets S^T[kv=16nf+4g+i][q=r]
    f32x4 s[8] = {};
    __builtin_amdgcn_s_setprio(1);
    #pragma unroll
    for (int nf = 0; nf < 8; ++nf)
      #pragma unroll
      for (int kc = 0; kc < 4; ++kc) {
        long long kf = *(const long long*)(Kc + (nf * 16 + r) * 128
                                           + ((kc * 32 + g * 8) ^ fx));
        s[nf] = MFMA8(kf, qf[kc], s[nf]);
      }
    __builtin_amdgcn_s_setprio(0);

    // ---- P = 2^(s*escale), packed e4m3 via hw cvt (bias cancels via ones-MFMA l)
    #pragma unroll
    for (int nf = 0; nf < 8; ++nf) {
      float p0 = exp2a(s[nf][0] * escale), p1 = exp2a(s[nf][1] * escale),
            p2 = exp2a(s[nf][2] * escale), p3 = exp2a(s[nf][3] * escale);
      uint32_t w = 0;
      w = (uint32_t)__builtin_amdgcn_cvt_pk_fp8_f32(p0, p1, (int)w, false);
      w = (uint32_t)__builtin_amdgcn_cvt_pk_fp8_f32(p2, p3, (int)w, true);
      *(uint32_t*)(Pw + r * 128 + ((nf * 16 + g * 4) ^ fx)) = w;
    }

    // ---- O += P @ V ; l += P @ ones  (A=P rows=q, B=V cols=d)
    __builtin_amdgcn_s_setprio(1);
    #pragma unroll
    for (int kc = 0; kc < 4; ++kc) {
      long long pa = *(const long long*)(Pw + r * 128 + ((kc * 32 + g * 8) ^ fx));
      ol = MFMA8(pa, ONES, ol);
      #pragma unroll
      for (int nf2 = 0; nf2 < 8; ++nf2) {
        long long vf = *(const long long*)(Vc + (nf2 * 16 + r) * 128
                                           + ((kc * 32 + g * 8) ^ fx));
        o[nf2] = MFMA8(pa, vf, o[nf2]);
      }
    }
    __builtin_amdgcn_s_setprio(0);
    __syncthreads();
    cur ^= 1;
  }

  // ---- epilogue: retrieved = (O_enc / l) / 32 ; no cross-lane needed
  float invA[4];
  #pragma unroll
  for (int i = 0; i < 4; ++i) invA[i] = 0.03125f / ol[i];
  unsigned short* rr = ret + ((size_t)(b * S_) + s0 + wave * 16) * E_ + h * D_;
  #pragma unroll
  for (int nf2 = 0; nf2 < 8; ++nf2)
    #pragma unroll
    for (int i = 0; i < 4; ++i)
      rr[(size_t)(g * 4 + i) * E_ + nf2 * 16 + r] = f2bf(o[nf2][i] * invA[i]);
}

// ---------------- final: out = query + rmsnorm(retrieved)*w ----------------
__global__ __launch_bounds__(256) void final_kernel(
    const unsigned short* __restrict__ ret, const float* __restrict__ w,
    const float* __restrict__ query, float* __restrict__ out)
{
  const int row = blockIdx.x;
  const int tid = threadIdx.x;
  u16x8 hv = *(const u16x8*)(ret + (size_t)row * E_ + tid * 8);
  float x[8];
  float ss = 0.f;
  #pragma unroll
  for (int j = 0; j < 8; ++j) { x[j] = bf2f(hv[j]); ss += x[j] * x[j]; }
  float tot = block_sum(ss);
  float sc = rsqrtf(tot * (1.0f / E_) + 1e-5f);
  const float* qr = query + (size_t)row * E_ + tid * 8;
  const float* wr = w + tid * 8;
  float o[8];
  #pragma unroll
  for (int j = 0; j < 8; ++j) o[j] = qr[j] + x[j] * sc * wr[j];
  float4* op = (float4*)(out + (size_t)row * E_ + tid * 8);
  op[0] = make_float4(o[0], o[1], o[2], o[3]);
  op[1] = make_float4(o[4], o[5], o[6], o[7]);
}

extern "C" void kernel_launch(void* const* d_in, const int* in_sizes, int n_in,
                              void* d_out, int out_size, void* d_ws, size_t ws_size,
                              hipStream_t stream) {
  const float* query = (const float*)d_in[0];
  const float* sp    = (const float*)d_in[1];
  const float* wq    = (const float*)d_in[2];
  const float* wk    = (const float*)d_in[3];
  const float* wv    = (const float*)d_in[4];
  const float* beta  = (const float*)d_in[5];
  const float* nqw   = (const float*)d_in[6];
  const float* nrw   = (const float*)d_in[7];
  float* out = (float*)d_out;

  char* ws = (char*)d_ws;
  unsigned short* wqb = (unsigned short*)(ws + 0);                    // 8 MB
  unsigned short* qn  = (unsigned short*)(ws + ((size_t)8 << 20));    // 16 MB
  unsigned char*  qb  = (unsigned char*)(ws + ((size_t)24 << 20));    // 8 MB (fp8)
  unsigned char*  kb  = (unsigned char*)(ws + ((size_t)32 << 20));    // 4 MB (fp8)
  unsigned char*  vtb = (unsigned char*)(ws + ((size_t)36 << 20));    // 4 MB (fp8)
  unsigned short* ret = qn;  // reuse (qn dead after q-GEMM)

  f32_to_bf16_kernel<<<4096, 256, 0, stream>>>(wq, wqb, E_ * E_ / 4);
  rmsnorm_q_kernel<<<B_ * S_, 256, 0, stream>>>(query, nqw, qn);
  gemm_qproj<<<(B_ * S_ / 128) * (E_ / 128), 256, 0, stream>>>(
      qn, wqb, qb, B_ * S_, E_, E_);
  proj_kv_kernel<<<dim3(M_ / 128, H_), 256, 0, stream>>>(sp, wk, wv, kb, vtb);
  attn_kernel<<<dim3(S_ / 128, H_, B_), 512, 0, stream>>>(qb, kb, vtb, beta, ret);
  final_kernel<<<B_ * S_, 256, 0, stream>>>(ret, nrw, query, out);
}

// Round 13
// 168.436 us; speedup vs baseline: 1.6455x; 1.6455x over previous
//
#include <hip/hip_runtime.h>
#include <hip/hip_bf16.h>
#include <stdint.h>

typedef __attribute__((ext_vector_type(8))) short bf16x8;
typedef __attribute__((ext_vector_type(4))) float f32x4;
typedef __attribute__((ext_vector_type(8))) unsigned short u16x8;
typedef __attribute__((ext_vector_type(4))) unsigned short u16x4;

#define B_ 2
#define S_ 2048
#define E_ 2048
#define H_ 16
#define M_ 2048
#define D_ 128

#define MFMA16(a, b, c) __builtin_amdgcn_mfma_f32_16x16x32_bf16(a, b, c, 0, 0, 0)
#define MFMA8(a, b, c) __builtin_amdgcn_mfma_f32_16x16x32_fp8_fp8(a, b, c, 0, 0, 0)

__device__ inline unsigned short f2bf(float f) {
  union { float f; unsigned u; } v; v.f = f;
  unsigned r = v.u + 0x7FFFu + ((v.u >> 16) & 1u);
  return (unsigned short)(r >> 16);
}
__device__ inline float bf2f(unsigned short h) {
  union { unsigned u; float f; } v; v.u = ((unsigned)h) << 16;
  return v.f;
}

// f32 -> e4m3 single byte via HW converter (branch-free; verified by r12 attn)
__device__ inline unsigned char f2e8(float f) {
  return (unsigned char)(__builtin_amdgcn_cvt_pk_fp8_f32(f, f, 0, false) & 0xFF);
}

// native 2^x
__device__ inline float exp2a(float x) {
  float r;
  asm("v_exp_f32 %0, %1" : "=v"(r) : "v"(x));
  return r;
}

__device__ inline void gload_lds16(const void* g, void* l) {
  __builtin_amdgcn_global_load_lds(
      (__attribute__((address_space(1))) void*)g,
      (__attribute__((address_space(3))) void*)l, 16, 0, 0);
}

__device__ inline bf16x8 pack8(float4 f0, float4 f1) {
  bf16x8 o;
  o[0] = (short)f2bf(f0.x); o[1] = (short)f2bf(f0.y);
  o[2] = (short)f2bf(f0.z); o[3] = (short)f2bf(f0.w);
  o[4] = (short)f2bf(f1.x); o[5] = (short)f2bf(f1.y);
  o[6] = (short)f2bf(f1.z); o[7] = (short)f2bf(f1.w);
  return o;
}

__device__ inline float block_sum(float v) {
  __shared__ float red[4];
  #pragma unroll
  for (int o = 32; o > 0; o >>= 1) v += __shfl_xor(v, o);
  int tid = threadIdx.x;
  if ((tid & 63) == 0) red[tid >> 6] = v;
  __syncthreads();
  return red[0] + red[1] + red[2] + red[3];
}

// ---------------- f32 -> bf16 convert (wq) ----------------
__global__ __launch_bounds__(256) void f32_to_bf16_kernel(
    const float* __restrict__ in, unsigned short* __restrict__ out, int n4)
{
  int i = blockIdx.x * 256 + threadIdx.x;
  if (i >= n4) return;
  float4 v = ((const float4*)in)[i];
  u16x4 o;
  o[0] = f2bf(v.x); o[1] = f2bf(v.y); o[2] = f2bf(v.z); o[3] = f2bf(v.w);
  *(u16x4*)(out + (size_t)i * 4) = o;
}

// ---------------- RMSNorm(query) -> bf16 qn ----------------
__global__ __launch_bounds__(256) void rmsnorm_q_kernel(
    const float* __restrict__ x, const float* __restrict__ w,
    unsigned short* __restrict__ y)
{
  const int row = blockIdx.x;
  const int tid = threadIdx.x;
  const float* xr = x + (size_t)row * E_;
  float4 v0 = ((const float4*)xr)[tid * 2];
  float4 v1 = ((const float4*)xr)[tid * 2 + 1];
  float ss = v0.x*v0.x + v0.y*v0.y + v0.z*v0.z + v0.w*v0.w
           + v1.x*v1.x + v1.y*v1.y + v1.z*v1.z + v1.w*v1.w;
  float tot = block_sum(ss);
  float sc = rsqrtf(tot * (1.0f / E_) + 1e-5f);
  float vals[8] = {v0.x, v0.y, v0.z, v0.w, v1.x, v1.y, v1.z, v1.w};
  const float* wr = w + tid * 8;
  u16x8 o;
  #pragma unroll
  for (int j = 0; j < 8; ++j) o[j] = f2bf(vals[j] * sc * wr[j]);
  *(u16x8*)(y + (size_t)row * E_ + tid * 8) = o;
}

// ---------------- GEMM C[M,N] = A[M,K] @ B[N,K]^T (bf16 in, fp8 out) ----------------
__global__ __launch_bounds__(256) void gemm_qproj(
    const unsigned short* __restrict__ A, const unsigned short* __restrict__ B,
    unsigned char* __restrict__ C, int M, int N, int K)
{
  __shared__ __align__(16) unsigned short As[128 * 64];  // 16KB
  __shared__ __align__(16) unsigned short Bs[128 * 64];  // 16KB
  const int nwg = gridDim.x;
  const int cpx = nwg >> 3;
  const int swz = (blockIdx.x & 7) * cpx + (blockIdx.x >> 3);
  const int mt = M >> 7;
  const int bm = (swz % mt) * 128;
  const int bn = (swz / mt) * 128;
  const int tid = threadIdx.x;
  const int wave = tid >> 6, lane = tid & 63;
  const int r = lane & 15, g = lane >> 4;
  const int wm = (wave >> 1) * 64, wn = (wave & 1) * 64;
  const int fx = (r & 7) << 4;

  f32x4 acc[4][4] = {};

  for (int k0 = 0; k0 < K; k0 += 64) {
    #pragma unroll
    for (int c = 0; c < 4; ++c) {
      int chunk = wave * 4 + c;
      int off = chunk * 1024 + lane * 16;
      int row = off >> 7;
      int cb = (off & 127) ^ ((row & 7) << 4);
      gload_lds16((const char*)A + ((size_t)(bm + row) * K + k0) * 2 + cb,
                  (char*)As + chunk * 1024);
      gload_lds16((const char*)B + ((size_t)(bn + row) * K + k0) * 2 + cb,
                  (char*)Bs + chunk * 1024);
    }
    __syncthreads();
    #pragma unroll
    for (int kc = 0; kc < 2; ++kc) {
      bf16x8 a[4], bb[4];
      #pragma unroll
      for (int m = 0; m < 4; ++m)
        a[m] = *(const bf16x8*)((const char*)As + (wm + m * 16 + r) * 128
                                + ((kc * 64 + g * 16) ^ fx));
      #pragma unroll
      for (int n = 0; n < 4; ++n)
        bb[n] = *(const bf16x8*)((const char*)Bs + (wn + n * 16 + r) * 128
                                 + ((kc * 64 + g * 16) ^ fx));
      #pragma unroll
      for (int m = 0; m < 4; ++m)
        #pragma unroll
        for (int n = 0; n < 4; ++n)
          acc[m][n] = MFMA16(a[m], bb[n], acc[m][n]);
    }
    __syncthreads();
  }
  #pragma unroll
  for (int m = 0; m < 4; ++m)
    #pragma unroll
    for (int n = 0; n < 4; ++n)
      #pragma unroll
      for (int i = 0; i < 4; ++i) {
        int row = bm + wm + m * 16 + g * 4 + i;
        int col = bn + wn + n * 16 + r;
        C[(size_t)row * N + col] = f2e8(acc[m][n][i]);
      }
}

// ---------------- fused per-head K AND V projections (fp8 out, x32 encode) ----------------
// kout[h][m][d] = e4m3( (sum sp*wk) * 32 );  vt[h][d][m] = e4m3( (sum sp*wv) * 32 )
// m-tile 64 -> 512 blocks (2/CU) for latency hiding; HW cvt encode (branch-free;
// r12's software-RNE encode was instruction-bound: 94% idle, 131us).
__global__ __launch_bounds__(256, 2) void proj_kv_kernel(
    const float* __restrict__ sp, const float* __restrict__ wk,
    const float* __restrict__ wv,
    unsigned char* __restrict__ kout, unsigned char* __restrict__ vtout)
{
  const int m0 = blockIdx.x * 64;
  const int h = blockIdx.y;
  const int tid = threadIdx.x, wave = tid >> 6, lane = tid & 63;
  const int r = lane & 15, g = lane >> 4;
  const int wm = (wave >> 1) * 32, wn = (wave & 1) * 64;
  const float* spb = sp + ((size_t)h * M_ + m0) * D_;
  f32x4 acck[2][4] = {};
  f32x4 accv[2][4] = {};
  #pragma unroll
  for (int kc = 0; kc < 4; ++kc) {
    bf16x8 a[2], bk[4], bv[4];
    #pragma unroll
    for (int m = 0; m < 2; ++m) {
      const float* p = spb + (size_t)(wm + m * 16 + r) * D_ + kc * 32 + g * 8;
      a[m] = pack8(*(const float4*)p, *(const float4*)(p + 4));
    }
    #pragma unroll
    for (int n = 0; n < 4; ++n) {
      const float* pk = wk + (size_t)(wn + n * 16 + r) * D_ + kc * 32 + g * 8;
      bk[n] = pack8(*(const float4*)pk, *(const float4*)(pk + 4));
      const float* pv = wv + (size_t)(wn + n * 16 + r) * D_ + kc * 32 + g * 8;
      bv[n] = pack8(*(const float4*)pv, *(const float4*)(pv + 4));
    }
    #pragma unroll
    for (int m = 0; m < 2; ++m)
      #pragma unroll
      for (int n = 0; n < 4; ++n) {
        acck[m][n] = MFMA16(a[m], bk[n], acck[m][n]);
        accv[m][n] = MFMA16(a[m], bv[n], accv[m][n]);
      }
  }
  #pragma unroll
  for (int m = 0; m < 2; ++m)
    #pragma unroll
    for (int n = 0; n < 4; ++n)
      #pragma unroll
      for (int i = 0; i < 4; ++i) {
        kout[((size_t)h * M_ + m0 + wm + m * 16 + g * 4 + i) * D_ + wn + n * 16 + r]
            = f2e8(acck[m][n][i] * 32.0f);
        vtout[((size_t)h * D_ + wn + n * 16 + r) * M_ + m0 + wm + m * 16 + g * 4 + i]
            = f2e8(accv[m][n][i] * 32.0f);
      }
}

// ---------------- flash attention over memory slots (fp8 K/Q/V/P) ----------------
// grid: (S/128, H, B); block 512 (8 waves x 16 q-rows); KVBLK=128.
// Same byte-layout/swizzle/dbuf structure as the verified bf16 r7 kernel
// (16KB tiles, 128B rows, (row&7)<<4 XOR both sides) but fp8 elements:
// LDS traffic per wave halves (the measured binding resource).
// l computed by an extra MFMA against a ones-fragment -> exact cancellation
// of P's quantization bias, and no epilogue shuffle/transpose needed.
// [r12 verified: 277us total run passed at absmax 0.0469 with attn ~62us]
__global__ __launch_bounds__(512, 4) void attn_kernel(
    const unsigned char* __restrict__ q,    // [B*S][E] e4m3 (natural scale)
    const unsigned char* __restrict__ kb,   // [H][M][D] e4m3 (x32)
    const unsigned char* __restrict__ vtb,  // [H][D][M] e4m3 (x32)
    const float* __restrict__ beta,
    unsigned short* __restrict__ ret)       // [B*S][E] bf16
{
  __shared__ __align__(16) unsigned char Ks[2][128 * 128];  // 2 x 16KB
  __shared__ __align__(16) unsigned char Vs[2][128 * 128];  // 2 x 16KB
  __shared__ __align__(16) unsigned char Ps[8][16 * 128];   // 16KB
  const int s0 = blockIdx.x * 128;
  const int h = blockIdx.y;
  const int b = blockIdx.z;
  const int tid = threadIdx.x, wave = tid >> 6, lane = tid & 63;
  const int r = lane & 15, g = lane >> 4;
  const int fx = (r & 7) << 4;
  // s_true*log2e*beta/sqrt(D) = s_f32 * escale  (k was encoded x32)
  const float escale = beta[h] * (0.08838834764831845f * 1.4426950408889634f / 32.0f);

  // Q fragment: 16 rows per wave (q-row = wave*16 + r), 8 bytes per kc
  long long qf[4];
  {
    const unsigned char* qr0 =
        q + ((size_t)(b * S_) + s0 + wave * 16 + r) * E_ + h * D_;
    #pragma unroll
    for (int kc = 0; kc < 4; ++kc)
      qf[kc] = *(const long long*)(qr0 + kc * 32 + g * 8);
  }

  const unsigned char* Kh = kb + (size_t)h * M_ * D_;
  const unsigned char* Vh = vtb + (size_t)h * D_ * M_;
  unsigned char* Pw = Ps[wave];
  const long long ONES = 0x3838383838383838LL;  // e4m3 1.0 x8

  f32x4 o[8] = {};
  f32x4 ol = {};

  auto stage = [&](int buf, int m0) {
    #pragma unroll
    for (int c = 0; c < 2; ++c) {
      int chunk = wave * 2 + c;           // 16 x 1KB chunks per 16KB tile
      int off = chunk * 1024 + lane * 16;
      int row = off >> 7;                 // 128B rows
      int cb = (off & 127) ^ ((row & 7) << 4);
      gload_lds16(Kh + (size_t)(m0 + row) * 128 + cb, (char*)Ks[buf] + chunk * 1024);
      gload_lds16(Vh + (size_t)row * M_ + m0 + cb, (char*)Vs[buf] + chunk * 1024);
    }
  };

  stage(0, 0);
  __syncthreads();

  int cur = 0;
  for (int t = 0; t < M_ / 128; ++t) {
    if (t + 1 < M_ / 128) stage(cur ^ 1, (t + 1) * 128);

    const unsigned char* Kc = Ks[cur];
    const unsigned char* Vc = Vs[cur];

    // ---- S^T = K @ Q^T : lane (r,g) gets S^T[kv=16nf+4g+i][q=r]
    f32x4 s[8] = {};
    __builtin_amdgcn_s_setprio(1);
    #pragma unroll
    for (int nf = 0; nf < 8; ++nf)
      #pragma unroll
      for (int kc = 0; kc < 4; ++kc) {
        long long kf = *(const long long*)(Kc + (nf * 16 + r) * 128
                                           + ((kc * 32 + g * 8) ^ fx));
        s[nf] = MFMA8(kf, qf[kc], s[nf]);
      }
    __builtin_amdgcn_s_setprio(0);

    // ---- P = 2^(s*escale), packed e4m3 via hw cvt (bias cancels via ones-MFMA l)
    #pragma unroll
    for (int nf = 0; nf < 8; ++nf) {
      float p0 = exp2a(s[nf][0] * escale), p1 = exp2a(s[nf][1] * escale),
            p2 = exp2a(s[nf][2] * escale), p3 = exp2a(s[nf][3] * escale);
      uint32_t w = 0;
      w = (uint32_t)__builtin_amdgcn_cvt_pk_fp8_f32(p0, p1, (int)w, false);
      w = (uint32_t)__builtin_amdgcn_cvt_pk_fp8_f32(p2, p3, (int)w, true);
      *(uint32_t*)(Pw + r * 128 + ((nf * 16 + g * 4) ^ fx)) = w;
    }

    // ---- O += P @ V ; l += P @ ones  (A=P rows=q, B=V cols=d)
    __builtin_amdgcn_s_setprio(1);
    #pragma unroll
    for (int kc = 0; kc < 4; ++kc) {
      long long pa = *(const long long*)(Pw + r * 128 + ((kc * 32 + g * 8) ^ fx));
      ol = MFMA8(pa, ONES, ol);
      #pragma unroll
      for (int nf2 = 0; nf2 < 8; ++nf2) {
        long long vf = *(const long long*)(Vc + (nf2 * 16 + r) * 128
                                           + ((kc * 32 + g * 8) ^ fx));
        o[nf2] = MFMA8(pa, vf, o[nf2]);
      }
    }
    __builtin_amdgcn_s_setprio(0);
    __syncthreads();
    cur ^= 1;
  }

  // ---- epilogue: retrieved = (O_enc / l) / 32 ; no cross-lane needed
  float invA[4];
  #pragma unroll
  for (int i = 0; i < 4; ++i) invA[i] = 0.03125f / ol[i];
  unsigned short* rr = ret + ((size_t)(b * S_) + s0 + wave * 16) * E_ + h * D_;
  #pragma unroll
  for (int nf2 = 0; nf2 < 8; ++nf2)
    #pragma unroll
    for (int i = 0; i < 4; ++i)
      rr[(size_t)(g * 4 + i) * E_ + nf2 * 16 + r] = f2bf(o[nf2][i] * invA[i]);
}

// ---------------- final: out = query + rmsnorm(retrieved)*w ----------------
__global__ __launch_bounds__(256) void final_kernel(
    const unsigned short* __restrict__ ret, const float* __restrict__ w,
    const float* __restrict__ query, float* __restrict__ out)
{
  const int row = blockIdx.x;
  const int tid = threadIdx.x;
  u16x8 hv = *(const u16x8*)(ret + (size_t)row * E_ + tid * 8);
  float x[8];
  float ss = 0.f;
  #pragma unroll
  for (int j = 0; j < 8; ++j) { x[j] = bf2f(hv[j]); ss += x[j] * x[j]; }
  float tot = block_sum(ss);
  float sc = rsqrtf(tot * (1.0f / E_) + 1e-5f);
  const float* qr = query + (size_t)row * E_ + tid * 8;
  const float* wr = w + tid * 8;
  float o[8];
  #pragma unroll
  for (int j = 0; j < 8; ++j) o[j] = qr[j] + x[j] * sc * wr[j];
  float4* op = (float4*)(out + (size_t)row * E_ + tid * 8);
  op[0] = make_float4(o[0], o[1], o[2], o[3]);
  op[1] = make_float4(o[4], o[5], o[6], o[7]);
}

extern "C" void kernel_launch(void* const* d_in, const int* in_sizes, int n_in,
                              void* d_out, int out_size, void* d_ws, size_t ws_size,
                              hipStream_t stream) {
  const float* query = (const float*)d_in[0];
  const float* sp    = (const float*)d_in[1];
  const float* wq    = (const float*)d_in[2];
  const float* wk    = (const float*)d_in[3];
  const float* wv    = (const float*)d_in[4];
  const float* beta  = (const float*)d_in[5];
  const float* nqw   = (const float*)d_in[6];
  const float* nrw   = (const float*)d_in[7];
  float* out = (float*)d_out;

  char* ws = (char*)d_ws;
  unsigned short* wqb = (unsigned short*)(ws + 0);                    // 8 MB
  unsigned short* qn  = (unsigned short*)(ws + ((size_t)8 << 20));    // 16 MB
  unsigned char*  qb  = (unsigned char*)(ws + ((size_t)24 << 20));    // 8 MB (fp8)
  unsigned char*  kb  = (unsigned char*)(ws + ((size_t)32 << 20));    // 4 MB (fp8)
  unsigned char*  vtb = (unsigned char*)(ws + ((size_t)36 << 20));    // 4 MB (fp8)
  unsigned short* ret = qn;  // reuse (qn dead after q-GEMM)

  f32_to_bf16_kernel<<<4096, 256, 0, stream>>>(wq, wqb, E_ * E_ / 4);
  rmsnorm_q_kernel<<<B_ * S_, 256, 0, stream>>>(query, nqw, qn);
  gemm_qproj<<<(B_ * S_ / 128) * (E_ / 128), 256, 0, stream>>>(
      qn, wqb, qb, B_ * S_, E_, E_);
  proj_kv_kernel<<<dim3(M_ / 64, H_), 256, 0, stream>>>(sp, wk, wv, kb, vtb);
  attn_kernel<<<dim3(S_ / 128, H_, B_), 512, 0, stream>>>(qb, kb, vtb, beta, ret);
  final_kernel<<<B_ * S_, 256, 0, stream>>>(ret, nrw, query, out);
}

// Round 14
// 149.535 us; speedup vs baseline: 1.8535x; 1.1264x over previous
//
#include <hip/hip_runtime.h>
#include <hip/hip_bf16.h>
#include <stdint.h>

typedef __attribute__((ext_vector_type(8))) short bf16x8;
typedef __attribute__((ext_vector_type(4))) float f32x4;
typedef __attribute__((ext_vector_type(8))) unsigned short u16x8;
typedef __attribute__((ext_vector_type(4))) unsigned short u16x4;
typedef __attribute__((ext_vector_type(2))) unsigned long long ull2;

#define B_ 2
#define S_ 2048
#define E_ 2048
#define H_ 16
#define M_ 2048
#define D_ 128

#define MFMA16(a, b, c) __builtin_amdgcn_mfma_f32_16x16x32_bf16(a, b, c, 0, 0, 0)
#define MFMA8(a, b, c) __builtin_amdgcn_mfma_f32_16x16x32_fp8_fp8(a, b, c, 0, 0, 0)

__device__ inline unsigned short f2bf(float f) {
  union { float f; unsigned u; } v; v.f = f;
  unsigned r = v.u + 0x7FFFu + ((v.u >> 16) & 1u);
  return (unsigned short)(r >> 16);
}
__device__ inline float bf2f(unsigned short h) {
  union { unsigned u; float f; } v; v.u = ((unsigned)h) << 16;
  return v.f;
}

// f32 -> e4m3 single byte via HW converter (branch-free; verified r12/r13)
__device__ inline unsigned char f2e8(float f) {
  return (unsigned char)(__builtin_amdgcn_cvt_pk_fp8_f32(f, f, 0, false) & 0xFF);
}

// native 2^x
__device__ inline float exp2a(float x) {
  float r;
  asm("v_exp_f32 %0, %1" : "=v"(r) : "v"(x));
  return r;
}

__device__ inline void gload_lds16(const void* g, void* l) {
  __builtin_amdgcn_global_load_lds(
      (__attribute__((address_space(1))) void*)g,
      (__attribute__((address_space(3))) void*)l, 16, 0, 0);
}

__device__ inline bf16x8 pack8(float4 f0, float4 f1) {
  bf16x8 o;
  o[0] = (short)f2bf(f0.x); o[1] = (short)f2bf(f0.y);
  o[2] = (short)f2bf(f0.z); o[3] = (short)f2bf(f0.w);
  o[4] = (short)f2bf(f1.x); o[5] = (short)f2bf(f1.y);
  o[6] = (short)f2bf(f1.z); o[7] = (short)f2bf(f1.w);
  return o;
}

__device__ inline float block_sum(float v) {
  __shared__ float red[4];
  #pragma unroll
  for (int o = 32; o > 0; o >>= 1) v += __shfl_xor(v, o);
  int tid = threadIdx.x;
  if ((tid & 63) == 0) red[tid >> 6] = v;
  __syncthreads();
  return red[0] + red[1] + red[2] + red[3];
}

// ---------------- f32 -> bf16 convert (wq) ----------------
__global__ __launch_bounds__(256) void f32_to_bf16_kernel(
    const float* __restrict__ in, unsigned short* __restrict__ out, int n4)
{
  int i = blockIdx.x * 256 + threadIdx.x;
  if (i >= n4) return;
  float4 v = ((const float4*)in)[i];
  u16x4 o;
  o[0] = f2bf(v.x); o[1] = f2bf(v.y); o[2] = f2bf(v.z); o[3] = f2bf(v.w);
  *(u16x4*)(out + (size_t)i * 4) = o;
}

// ---------------- RMSNorm(query) -> bf16 qn ----------------
__global__ __launch_bounds__(256) void rmsnorm_q_kernel(
    const float* __restrict__ x, const float* __restrict__ w,
    unsigned short* __restrict__ y)
{
  const int row = blockIdx.x;
  const int tid = threadIdx.x;
  const float* xr = x + (size_t)row * E_;
  float4 v0 = ((const float4*)xr)[tid * 2];
  float4 v1 = ((const float4*)xr)[tid * 2 + 1];
  float ss = v0.x*v0.x + v0.y*v0.y + v0.z*v0.z + v0.w*v0.w
           + v1.x*v1.x + v1.y*v1.y + v1.z*v1.z + v1.w*v1.w;
  float tot = block_sum(ss);
  float sc = rsqrtf(tot * (1.0f / E_) + 1e-5f);
  float vals[8] = {v0.x, v0.y, v0.z, v0.w, v1.x, v1.y, v1.z, v1.w};
  const float* wr = w + tid * 8;
  u16x8 o;
  #pragma unroll
  for (int j = 0; j < 8; ++j) o[j] = f2bf(vals[j] * sc * wr[j]);
  *(u16x8*)(y + (size_t)row * E_ + tid * 8) = o;
}

// ---------------- GEMM C[M,N] = A[M,K] @ B[N,K]^T (bf16 in, fp8 out) ----------------
__global__ __launch_bounds__(256) void gemm_qproj(
    const unsigned short* __restrict__ A, const unsigned short* __restrict__ B,
    unsigned char* __restrict__ C, int M, int N, int K)
{
  __shared__ __align__(16) unsigned short As[128 * 64];  // 16KB
  __shared__ __align__(16) unsigned short Bs[128 * 64];  // 16KB
  const int nwg = gridDim.x;
  const int cpx = nwg >> 3;
  const int swz = (blockIdx.x & 7) * cpx + (blockIdx.x >> 3);
  const int mt = M >> 7;
  const int bm = (swz % mt) * 128;
  const int bn = (swz / mt) * 128;
  const int tid = threadIdx.x;
  const int wave = tid >> 6, lane = tid & 63;
  const int r = lane & 15, g = lane >> 4;
  const int wm = (wave >> 1) * 64, wn = (wave & 1) * 64;
  const int fx = (r & 7) << 4;

  f32x4 acc[4][4] = {};

  for (int k0 = 0; k0 < K; k0 += 64) {
    #pragma unroll
    for (int c = 0; c < 4; ++c) {
      int chunk = wave * 4 + c;
      int off = chunk * 1024 + lane * 16;
      int row = off >> 7;
      int cb = (off & 127) ^ ((row & 7) << 4);
      gload_lds16((const char*)A + ((size_t)(bm + row) * K + k0) * 2 + cb,
                  (char*)As + chunk * 1024);
      gload_lds16((const char*)B + ((size_t)(bn + row) * K + k0) * 2 + cb,
                  (char*)Bs + chunk * 1024);
    }
    __syncthreads();
    #pragma unroll
    for (int kc = 0; kc < 2; ++kc) {
      bf16x8 a[4], bb[4];
      #pragma unroll
      for (int m = 0; m < 4; ++m)
        a[m] = *(const bf16x8*)((const char*)As + (wm + m * 16 + r) * 128
                                + ((kc * 64 + g * 16) ^ fx));
      #pragma unroll
      for (int n = 0; n < 4; ++n)
        bb[n] = *(const bf16x8*)((const char*)Bs + (wn + n * 16 + r) * 128
                                 + ((kc * 64 + g * 16) ^ fx));
      #pragma unroll
      for (int m = 0; m < 4; ++m)
        #pragma unroll
        for (int n = 0; n < 4; ++n)
          acc[m][n] = MFMA16(a[m], bb[n], acc[m][n]);
    }
    __syncthreads();
  }
  #pragma unroll
  for (int m = 0; m < 4; ++m)
    #pragma unroll
    for (int n = 0; n < 4; ++n)
      #pragma unroll
      for (int i = 0; i < 4; ++i) {
        int row = bm + wm + m * 16 + g * 4 + i;
        int col = bn + wn + n * 16 + r;
        C[(size_t)row * N + col] = f2e8(acc[m][n][i]);
      }
}

// ---------------- fused per-head K AND V projections (fp8 out, x32 encode) ----------------
// K/V^T stored with the k-dim byte-permutation pi (bits[6:5]<->[4:3]) so that
// attention's per-lane kc-fragments are 32B-contiguous -> ds_read_b128.
__global__ __launch_bounds__(256, 2) void proj_kv_kernel(
    const float* __restrict__ sp, const float* __restrict__ wk,
    const float* __restrict__ wv,
    unsigned char* __restrict__ kout, unsigned char* __restrict__ vtout)
{
  const int m0 = blockIdx.x * 64;
  const int h = blockIdx.y;
  const int tid = threadIdx.x, wave = tid >> 6, lane = tid & 63;
  const int r = lane & 15, g = lane >> 4;
  const int wm = (wave >> 1) * 32, wn = (wave & 1) * 64;
  const float* spb = sp + ((size_t)h * M_ + m0) * D_;
  f32x4 acck[2][4] = {};
  f32x4 accv[2][4] = {};
  #pragma unroll
  for (int kc = 0; kc < 4; ++kc) {
    bf16x8 a[2], bk[4], bv[4];
    #pragma unroll
    for (int m = 0; m < 2; ++m) {
      const float* p = spb + (size_t)(wm + m * 16 + r) * D_ + kc * 32 + g * 8;
      a[m] = pack8(*(const float4*)p, *(const float4*)(p + 4));
    }
    #pragma unroll
    for (int n = 0; n < 4; ++n) {
      const float* pk = wk + (size_t)(wn + n * 16 + r) * D_ + kc * 32 + g * 8;
      bk[n] = pack8(*(const float4*)pk, *(const float4*)(pk + 4));
      const float* pv = wv + (size_t)(wn + n * 16 + r) * D_ + kc * 32 + g * 8;
      bv[n] = pack8(*(const float4*)pv, *(const float4*)(pv + 4));
    }
    #pragma unroll
    for (int m = 0; m < 2; ++m)
      #pragma unroll
      for (int n = 0; n < 4; ++n) {
        acck[m][n] = MFMA16(a[m], bk[n], acck[m][n]);
        accv[m][n] = MFMA16(a[m], bv[n], accv[m][n]);
      }
  }
  #pragma unroll
  for (int m = 0; m < 2; ++m)
    #pragma unroll
    for (int n = 0; n < 4; ++n)
      #pragma unroll
      for (int i = 0; i < 4; ++i) {
        int d = wn + n * 16 + r;
        int dp = ((d >> 3) & 3) * 32 + ((d >> 5) & 3) * 8 + (d & 7);  // pi(d)
        kout[((size_t)h * M_ + m0 + wm + m * 16 + g * 4 + i) * D_ + dp]
            = f2e8(acck[m][n][i] * 32.0f);
        int mc = m0 + wm + m * 16 + g * 4 + i;
        int ml = mc & 127;
        int mp = (mc & ~127)
               | (((ml >> 3) & 3) * 32 + ((ml >> 5) & 3) * 8 + (ml & 7));  // pi within group
        vtout[((size_t)h * D_ + wn + n * 16 + r) * M_ + mp]
            = f2e8(accv[m][n][i] * 32.0f);
      }
}

// ---------------- flash attention over memory slots (fp8 K/Q/V/P) ----------------
// grid: (S/128, H, B); block 512 (8 waves x 16 q-rows); KVBLK=128.
// All LDS reads are ds_read_b128 via the pi-permuted k-dim layout (each lane's
// four kc fragments contiguous 32B). r13's b64 reads were 4-way bank-conflicted
// and issue-bound (68 b64/iter, conflicts 1.84e7); this halves issue count.
// Math is bitwise identical to r13 (same values, same MFMA order).
__global__ __launch_bounds__(512, 4) void attn_kernel(
    const unsigned char* __restrict__ q,    // [B*S][E] e4m3 (natural scale)
    const unsigned char* __restrict__ kb,   // [H][M][D] e4m3 (x32, pi-permuted d)
    const unsigned char* __restrict__ vtb,  // [H][D][M] e4m3 (x32, pi-permuted m%128)
    const float* __restrict__ beta,
    unsigned short* __restrict__ ret)       // [B*S][E] bf16
{
  __shared__ __align__(16) unsigned char Ks[2][128 * 128];  // 2 x 16KB
  __shared__ __align__(16) unsigned char Vs[2][128 * 128];  // 2 x 16KB
  __shared__ __align__(16) unsigned char Ps[8][16 * 128];   // 16KB
  const int s0 = blockIdx.x * 128;
  const int h = blockIdx.y;
  const int b = blockIdx.z;
  const int tid = threadIdx.x, wave = tid >> 6, lane = tid & 63;
  const int r = lane & 15, g = lane >> 4;
  const int fx = (r & 7) << 4;
  const float escale = beta[h] * (0.08838834764831845f * 1.4426950408889634f / 32.0f);

  // Q fragment: 16 rows per wave (q-row = wave*16 + r), 8 bytes per kc (layout unchanged)
  long long qf[4];
  {
    const unsigned char* qr0 =
        q + ((size_t)(b * S_) + s0 + wave * 16 + r) * E_ + h * D_;
    #pragma unroll
    for (int kc = 0; kc < 4; ++kc)
      qf[kc] = *(const long long*)(qr0 + kc * 32 + g * 8);
  }

  const unsigned char* Kh = kb + (size_t)h * M_ * D_;
  const unsigned char* Vh = vtb + (size_t)h * D_ * M_;
  unsigned char* Pw = Ps[wave];
  const long long ONES = 0x3838383838383838LL;  // e4m3 1.0 x8

  f32x4 o[8] = {};
  f32x4 ol = {};

  auto stage = [&](int buf, int m0) {
    #pragma unroll
    for (int c = 0; c < 2; ++c) {
      int chunk = wave * 2 + c;           // 16 x 1KB chunks per 16KB tile
      int off = chunk * 1024 + lane * 16;
      int row = off >> 7;                 // 128B rows
      int cb = (off & 127) ^ ((row & 7) << 4);
      gload_lds16(Kh + (size_t)(m0 + row) * 128 + cb, (char*)Ks[buf] + chunk * 1024);
      gload_lds16(Vh + (size_t)row * M_ + m0 + cb, (char*)Vs[buf] + chunk * 1024);
    }
  };

  stage(0, 0);
  __syncthreads();

  int cur = 0;
  for (int t = 0; t < M_ / 128; ++t) {
    if (t + 1 < M_ / 128) stage(cur ^ 1, (t + 1) * 128);

    const unsigned char* Kc = Ks[cur];
    const unsigned char* Vc = Vs[cur];

    // ---- S^T = K @ Q^T : lane (r,g) gets S^T[kv=16nf+4g+i][q=r]
    f32x4 s[8] = {};
    __builtin_amdgcn_s_setprio(1);
    #pragma unroll
    for (int nf = 0; nf < 8; ++nf) {
      const unsigned char* kr = Kc + (nf * 16 + r) * 128;
      ull2 ka = *(const ull2*)(kr + ((g * 32) ^ fx));        // kc0, kc1
      ull2 kb2 = *(const ull2*)(kr + ((g * 32 + 16) ^ fx));  // kc2, kc3
      s[nf] = MFMA8((long long)ka[0], qf[0], s[nf]);
      s[nf] = MFMA8((long long)ka[1], qf[1], s[nf]);
      s[nf] = MFMA8((long long)kb2[0], qf[2], s[nf]);
      s[nf] = MFMA8((long long)kb2[1], qf[3], s[nf]);
    }
    __builtin_amdgcn_s_setprio(0);

    // ---- P = 2^(s*escale), packed e4m3; b32 write at pi(slot) position
    #pragma unroll
    for (int nf = 0; nf < 8; ++nf) {
      float p0 = exp2a(s[nf][0] * escale), p1 = exp2a(s[nf][1] * escale),
            p2 = exp2a(s[nf][2] * escale), p3 = exp2a(s[nf][3] * escale);
      uint32_t w = 0;
      w = (uint32_t)__builtin_amdgcn_cvt_pk_fp8_f32(p0, p1, (int)w, false);
      w = (uint32_t)__builtin_amdgcn_cvt_pk_fp8_f32(p2, p3, (int)w, true);
      int pbase = ((nf & 1) * 2 + (g >> 1)) * 32 + (nf >> 1) * 8 + (g & 1) * 4;
      *(uint32_t*)(Pw + r * 128 + (pbase ^ fx)) = w;
    }

    // ---- O += P @ V ; l += P @ ones  (A=P row q=r, B=V^T row d)
    ull2 pa01 = *(const ull2*)(Pw + r * 128 + ((g * 32) ^ fx));       // kc0, kc1
    ull2 pa23 = *(const ull2*)(Pw + r * 128 + ((g * 32 + 16) ^ fx));  // kc2, kc3
    __builtin_amdgcn_s_setprio(1);
    ol = MFMA8((long long)pa01[0], ONES, ol);
    ol = MFMA8((long long)pa01[1], ONES, ol);
    ol = MFMA8((long long)pa23[0], ONES, ol);
    ol = MFMA8((long long)pa23[1], ONES, ol);
    #pragma unroll
    for (int nf2 = 0; nf2 < 8; ++nf2) {
      const unsigned char* vr = Vc + (nf2 * 16 + r) * 128;
      ull2 va = *(const ull2*)(vr + ((g * 32) ^ fx));
      ull2 vb2 = *(const ull2*)(vr + ((g * 32 + 16) ^ fx));
      o[nf2] = MFMA8((long long)pa01[0], (long long)va[0], o[nf2]);
      o[nf2] = MFMA8((long long)pa01[1], (long long)va[1], o[nf2]);
      o[nf2] = MFMA8((long long)pa23[0], (long long)vb2[0], o[nf2]);
      o[nf2] = MFMA8((long long)pa23[1], (long long)vb2[1], o[nf2]);
    }
    __builtin_amdgcn_s_setprio(0);
    __syncthreads();
    cur ^= 1;
  }

  // ---- epilogue: retrieved = (O_enc / l) / 32 ; no cross-lane needed
  float invA[4];
  #pragma unroll
  for (int i = 0; i < 4; ++i) invA[i] = 0.03125f / ol[i];
  unsigned short* rr = ret + ((size_t)(b * S_) + s0 + wave * 16) * E_ + h * D_;
  #pragma unroll
  for (int nf2 = 0; nf2 < 8; ++nf2)
    #pragma unroll
    for (int i = 0; i < 4; ++i)
      rr[(size_t)(g * 4 + i) * E_ + nf2 * 16 + r] = f2bf(o[nf2][i] * invA[i]);
}

// ---------------- final: out = query + rmsnorm(retrieved)*w ----------------
__global__ __launch_bounds__(256) void final_kernel(
    const unsigned short* __restrict__ ret, const float* __restrict__ w,
    const float* __restrict__ query, float* __restrict__ out)
{
  const int row = blockIdx.x;
  const int tid = threadIdx.x;
  u16x8 hv = *(const u16x8*)(ret + (size_t)row * E_ + tid * 8);
  float x[8];
  float ss = 0.f;
  #pragma unroll
  for (int j = 0; j < 8; ++j) { x[j] = bf2f(hv[j]); ss += x[j] * x[j]; }
  float tot = block_sum(ss);
  float sc = rsqrtf(tot * (1.0f / E_) + 1e-5f);
  const float* qr = query + (size_t)row * E_ + tid * 8;
  const float* wr = w + tid * 8;
  float o[8];
  #pragma unroll
  for (int j = 0; j < 8; ++j) o[j] = qr[j] + x[j] * sc * wr[j];
  float4* op = (float4*)(out + (size_t)row * E_ + tid * 8);
  op[0] = make_float4(o[0], o[1], o[2], o[3]);
  op[1] = make_float4(o[4], o[5], o[6], o[7]);
}

extern "C" void kernel_launch(void* const* d_in, const int* in_sizes, int n_in,
                              void* d_out, int out_size, void* d_ws, size_t ws_size,
                              hipStream_t stream) {
  const float* query = (const float*)d_in[0];
  const float* sp    = (const float*)d_in[1];
  const float* wq    = (const float*)d_in[2];
  const float* wk    = (const float*)d_in[3];
  const float* wv    = (const float*)d_in[4];
  const float* beta  = (const float*)d_in[5];
  const float* nqw   = (const float*)d_in[6];
  const float* nrw   = (const float*)d_in[7];
  float* out = (float*)d_out;

  char* ws = (char*)d_ws;
  unsigned short* wqb = (unsigned short*)(ws + 0);                    // 8 MB
  unsigned short* qn  = (unsigned short*)(ws + ((size_t)8 << 20));    // 16 MB
  unsigned char*  qb  = (unsigned char*)(ws + ((size_t)24 << 20));    // 8 MB (fp8)
  unsigned char*  kb  = (unsigned char*)(ws + ((size_t)32 << 20));    // 4 MB (fp8)
  unsigned char*  vtb = (unsigned char*)(ws + ((size_t)36 << 20));    // 4 MB (fp8)
  unsigned short* ret = qn;  // reuse (qn dead after q-GEMM)

  f32_to_bf16_kernel<<<4096, 256, 0, stream>>>(wq, wqb, E_ * E_ / 4);
  rmsnorm_q_kernel<<<B_ * S_, 256, 0, stream>>>(query, nqw, qn);
  gemm_qproj<<<(B_ * S_ / 128) * (E_ / 128), 256, 0, stream>>>(
      qn, wqb, qb, B_ * S_, E_, E_);
  proj_kv_kernel<<<dim3(M_ / 64, H_), 256, 0, stream>>>(sp, wk, wv, kb, vtb);
  attn_kernel<<<dim3(S_ / 128, H_, B_), 512, 0, stream>>>(qb, kb, vtb, beta, ret);
  final_kernel<<<B_ * S_, 256, 0, stream>>>(ret, nrw, query, out);
}

// Round 15
// 134.387 us; speedup vs baseline: 2.0625x; 1.1127x over previous
//
#include <hip/hip_runtime.h>
#include <hip/hip_bf16.h>
#include <stdint.h>

typedef __attribute__((ext_vector_type(8))) short bf16x8;
typedef __attribute__((ext_vector_type(4))) float f32x4;
typedef __attribute__((ext_vector_type(8))) unsigned short u16x8;
typedef __attribute__((ext_vector_type(4))) unsigned short u16x4;
typedef __attribute__((ext_vector_type(2))) unsigned long long ull2;

#define B_ 2
#define S_ 2048
#define E_ 2048
#define H_ 16
#define M_ 2048
#define D_ 128

#define MFMA16(a, b, c) __builtin_amdgcn_mfma_f32_16x16x32_bf16(a, b, c, 0, 0, 0)
#define MFMA8(a, b, c) __builtin_amdgcn_mfma_f32_16x16x32_fp8_fp8(a, b, c, 0, 0, 0)

__device__ inline unsigned short f2bf(float f) {
  union { float f; unsigned u; } v; v.f = f;
  unsigned r = v.u + 0x7FFFu + ((v.u >> 16) & 1u);
  return (unsigned short)(r >> 16);
}
__device__ inline float bf2f(unsigned short h) {
  union { unsigned u; float f; } v; v.u = ((unsigned)h) << 16;
  return v.f;
}

// f32 -> e4m3 single byte via HW converter (branch-free; verified r12-r14)
__device__ inline unsigned char f2e8(float f) {
  return (unsigned char)(__builtin_amdgcn_cvt_pk_fp8_f32(f, f, 0, false) & 0xFF);
}
// 4 floats -> 4 packed e4m3 bytes (verified pattern from attn P-pack)
__device__ inline uint32_t pk4e8(float a, float b, float c, float d) {
  uint32_t w = 0;
  w = (uint32_t)__builtin_amdgcn_cvt_pk_fp8_f32(a, b, (int)w, false);
  w = (uint32_t)__builtin_amdgcn_cvt_pk_fp8_f32(c, d, (int)w, true);
  return w;
}

// native 2^x
__device__ inline float exp2a(float x) {
  float r;
  asm("v_exp_f32 %0, %1" : "=v"(r) : "v"(x));
  return r;
}

__device__ inline void gload_lds16(const void* g, void* l) {
  __builtin_amdgcn_global_load_lds(
      (__attribute__((address_space(1))) void*)g,
      (__attribute__((address_space(3))) void*)l, 16, 0, 0);
}

__device__ inline bf16x8 pack8(float4 f0, float4 f1) {
  bf16x8 o;
  o[0] = (short)f2bf(f0.x); o[1] = (short)f2bf(f0.y);
  o[2] = (short)f2bf(f0.z); o[3] = (short)f2bf(f0.w);
  o[4] = (short)f2bf(f1.x); o[5] = (short)f2bf(f1.y);
  o[6] = (short)f2bf(f1.z); o[7] = (short)f2bf(f1.w);
  return o;
}

__device__ inline float block_sum(float v) {
  __shared__ float red[4];
  #pragma unroll
  for (int o = 32; o > 0; o >>= 1) v += __shfl_xor(v, o);
  int tid = threadIdx.x;
  if ((tid & 63) == 0) red[tid >> 6] = v;
  __syncthreads();
  return red[0] + red[1] + red[2] + red[3];
}

// pi(col) within a 128-col group: bits[6:5] <-> [4:3]  (col%8 preserved)
__device__ inline int pi_pos(int c) {
  return (c & ~127) | (((c >> 3) & 3) * 32) | (((c >> 5) & 3) * 8) | (c & 7);
}

// ---------------- f32 -> fp8 pi-permuted convert (wq) ----------------
__global__ __launch_bounds__(256) void f32_to_fp8_kernel(
    const float* __restrict__ in, unsigned char* __restrict__ out, int n8)
{
  int i = blockIdx.x * 256 + threadIdx.x;
  if (i >= n8) return;
  const float* p = in + (size_t)i * 8;
  float4 a = *(const float4*)p, b = *(const float4*)(p + 4);
  uint2 pk;
  pk.x = pk4e8(a.x, a.y, a.z, a.w);
  pk.y = pk4e8(b.x, b.y, b.z, b.w);
  size_t flat = (size_t)i * 8;
  int c = (int)(flat & (E_ - 1));        // col within K=2048 row
  *(uint2*)(out + (flat - c) + pi_pos(c)) = pk;
}

// ---------------- RMSNorm(query) -> fp8 qn (pi-permuted) ----------------
__global__ __launch_bounds__(256) void rmsnorm_q_kernel(
    const float* __restrict__ x, const float* __restrict__ w,
    unsigned char* __restrict__ y)
{
  const int row = blockIdx.x;
  const int tid = threadIdx.x;
  const float* xr = x + (size_t)row * E_;
  float4 v0 = ((const float4*)xr)[tid * 2];
  float4 v1 = ((const float4*)xr)[tid * 2 + 1];
  float ss = v0.x*v0.x + v0.y*v0.y + v0.z*v0.z + v0.w*v0.w
           + v1.x*v1.x + v1.y*v1.y + v1.z*v1.z + v1.w*v1.w;
  float tot = block_sum(ss);
  float sc = rsqrtf(tot * (1.0f / E_) + 1e-5f);
  float vals[8] = {v0.x, v0.y, v0.z, v0.w, v1.x, v1.y, v1.z, v1.w};
  const float* wr = w + tid * 8;
  float f[8];
  #pragma unroll
  for (int j = 0; j < 8; ++j) f[j] = vals[j] * sc * wr[j];
  uint2 pk;
  pk.x = pk4e8(f[0], f[1], f[2], f[3]);
  pk.y = pk4e8(f[4], f[5], f[6], f[7]);
  *(uint2*)(y + (size_t)row * E_ + pi_pos(tid * 8)) = pk;
}

// ---------------- GEMM C[M,N] = A[M,K] @ B[N,K]^T (fp8 in, fp8 out) ----------------
// BK=128, 128B pi-permuted rows (same verified byte-structure as attn K-tiles):
// staging pre-swizzles source with (row&7)<<4; fragments are 2 x b128 per row
// covering all four kc sub-blocks. A/B share the pi layout -> k-pairing exact.
__global__ __launch_bounds__(256) void gemm_qproj(
    const unsigned char* __restrict__ A, const unsigned char* __restrict__ B,
    unsigned char* __restrict__ C, int M, int N, int K)
{
  __shared__ __align__(16) unsigned char As[128 * 128];  // 16KB
  __shared__ __align__(16) unsigned char Bs[128 * 128];  // 16KB
  const int nwg = gridDim.x;
  const int cpx = nwg >> 3;
  const int swz = (blockIdx.x & 7) * cpx + (blockIdx.x >> 3);
  const int mt = M >> 7;
  const int bm = (swz % mt) * 128;
  const int bn = (swz / mt) * 128;
  const int tid = threadIdx.x;
  const int wave = tid >> 6, lane = tid & 63;
  const int r = lane & 15, g = lane >> 4;
  const int wm = (wave >> 1) * 64, wn = (wave & 1) * 64;
  const int fx = (r & 7) << 4;

  f32x4 acc[4][4] = {};

  for (int k0 = 0; k0 < K; k0 += 128) {
    #pragma unroll
    for (int c = 0; c < 4; ++c) {
      int chunk = wave * 4 + c;             // 16 x 1KB chunks per 16KB tile
      int off = chunk * 1024 + lane * 16;
      int row = off >> 7;                   // 128B rows
      int cb = (off & 127) ^ ((row & 7) << 4);
      gload_lds16(A + (size_t)(bm + row) * K + k0 + cb, (char*)As + chunk * 1024);
      gload_lds16(B + (size_t)(bn + row) * K + k0 + cb, (char*)Bs + chunk * 1024);
    }
    __syncthreads();
    #pragma unroll
    for (int half = 0; half < 2; ++half) {
      ull2 af[4], bf[4];
      #pragma unroll
      for (int m = 0; m < 4; ++m)
        af[m] = *(const ull2*)((const char*)As + (wm + m * 16 + r) * 128
                               + ((g * 32 + half * 16) ^ fx));
      #pragma unroll
      for (int n = 0; n < 4; ++n)
        bf[n] = *(const ull2*)((const char*)Bs + (wn + n * 16 + r) * 128
                               + ((g * 32 + half * 16) ^ fx));
      #pragma unroll
      for (int m = 0; m < 4; ++m)
        #pragma unroll
        for (int n = 0; n < 4; ++n) {
          acc[m][n] = MFMA8((long long)af[m][0], (long long)bf[n][0], acc[m][n]);
          acc[m][n] = MFMA8((long long)af[m][1], (long long)bf[n][1], acc[m][n]);
        }
    }
    __syncthreads();
  }
  #pragma unroll
  for (int m = 0; m < 4; ++m)
    #pragma unroll
    for (int n = 0; n < 4; ++n)
      #pragma unroll
      for (int i = 0; i < 4; ++i) {
        int row = bm + wm + m * 16 + g * 4 + i;
        int col = bn + wn + n * 16 + r;
        C[(size_t)row * N + col] = f2e8(acc[m][n][i]);
      }
}

// ---------------- fused per-head K AND V projections (fp8 out, x32 encode) ----------------
// K/V^T stored with the k-dim byte-permutation pi so attention reads b128.
__global__ __launch_bounds__(256, 2) void proj_kv_kernel(
    const float* __restrict__ sp, const float* __restrict__ wk,
    const float* __restrict__ wv,
    unsigned char* __restrict__ kout, unsigned char* __restrict__ vtout)
{
  const int m0 = blockIdx.x * 64;
  const int h = blockIdx.y;
  const int tid = threadIdx.x, wave = tid >> 6, lane = tid & 63;
  const int r = lane & 15, g = lane >> 4;
  const int wm = (wave >> 1) * 32, wn = (wave & 1) * 64;
  const float* spb = sp + ((size_t)h * M_ + m0) * D_;
  f32x4 acck[2][4] = {};
  f32x4 accv[2][4] = {};
  #pragma unroll
  for (int kc = 0; kc < 4; ++kc) {
    bf16x8 a[2], bk[4], bv[4];
    #pragma unroll
    for (int m = 0; m < 2; ++m) {
      const float* p = spb + (size_t)(wm + m * 16 + r) * D_ + kc * 32 + g * 8;
      a[m] = pack8(*(const float4*)p, *(const float4*)(p + 4));
    }
    #pragma unroll
    for (int n = 0; n < 4; ++n) {
      const float* pk = wk + (size_t)(wn + n * 16 + r) * D_ + kc * 32 + g * 8;
      bk[n] = pack8(*(const float4*)pk, *(const float4*)(pk + 4));
      const float* pv = wv + (size_t)(wn + n * 16 + r) * D_ + kc * 32 + g * 8;
      bv[n] = pack8(*(const float4*)pv, *(const float4*)(pv + 4));
    }
    #pragma unroll
    for (int m = 0; m < 2; ++m)
      #pragma unroll
      for (int n = 0; n < 4; ++n) {
        acck[m][n] = MFMA16(a[m], bk[n], acck[m][n]);
        accv[m][n] = MFMA16(a[m], bv[n], accv[m][n]);
      }
  }
  #pragma unroll
  for (int m = 0; m < 2; ++m)
    #pragma unroll
    for (int n = 0; n < 4; ++n)
      #pragma unroll
      for (int i = 0; i < 4; ++i) {
        int d = wn + n * 16 + r;
        kout[((size_t)h * M_ + m0 + wm + m * 16 + g * 4 + i) * D_ + pi_pos(d)]
            = f2e8(acck[m][n][i] * 32.0f);
        int mc = m0 + wm + m * 16 + g * 4 + i;
        int mp = (mc & ~127) | (pi_pos(mc & 127));
        vtout[((size_t)h * D_ + wn + n * 16 + r) * M_ + mp]
            = f2e8(accv[m][n][i] * 32.0f);
      }
}

// ---------------- flash attention over memory slots (fp8 K/Q/V/P) ----------------
// [r14 verified: 63.2us, MfmaUtil 44.8, absmax 0.046875 — byte-identical here]
__global__ __launch_bounds__(512, 4) void attn_kernel(
    const unsigned char* __restrict__ q,    // [B*S][E] e4m3 (natural scale)
    const unsigned char* __restrict__ kb,   // [H][M][D] e4m3 (x32, pi-permuted d)
    const unsigned char* __restrict__ vtb,  // [H][D][M] e4m3 (x32, pi-permuted m%128)
    const float* __restrict__ beta,
    unsigned short* __restrict__ ret)       // [B*S][E] bf16
{
  __shared__ __align__(16) unsigned char Ks[2][128 * 128];  // 2 x 16KB
  __shared__ __align__(16) unsigned char Vs[2][128 * 128];  // 2 x 16KB
  __shared__ __align__(16) unsigned char Ps[8][16 * 128];   // 16KB
  const int s0 = blockIdx.x * 128;
  const int h = blockIdx.y;
  const int b = blockIdx.z;
  const int tid = threadIdx.x, wave = tid >> 6, lane = tid & 63;
  const int r = lane & 15, g = lane >> 4;
  const int fx = (r & 7) << 4;
  const float escale = beta[h] * (0.08838834764831845f * 1.4426950408889634f / 32.0f);

  long long qf[4];
  {
    const unsigned char* qr0 =
        q + ((size_t)(b * S_) + s0 + wave * 16 + r) * E_ + h * D_;
    #pragma unroll
    for (int kc = 0; kc < 4; ++kc)
      qf[kc] = *(const long long*)(qr0 + kc * 32 + g * 8);
  }

  const unsigned char* Kh = kb + (size_t)h * M_ * D_;
  const unsigned char* Vh = vtb + (size_t)h * D_ * M_;
  unsigned char* Pw = Ps[wave];
  const long long ONES = 0x3838383838383838LL;  // e4m3 1.0 x8

  f32x4 o[8] = {};
  f32x4 ol = {};

  auto stage = [&](int buf, int m0) {
    #pragma unroll
    for (int c = 0; c < 2; ++c) {
      int chunk = wave * 2 + c;
      int off = chunk * 1024 + lane * 16;
      int row = off >> 7;
      int cb = (off & 127) ^ ((row & 7) << 4);
      gload_lds16(Kh + (size_t)(m0 + row) * 128 + cb, (char*)Ks[buf] + chunk * 1024);
      gload_lds16(Vh + (size_t)row * M_ + m0 + cb, (char*)Vs[buf] + chunk * 1024);
    }
  };

  stage(0, 0);
  __syncthreads();

  int cur = 0;
  for (int t = 0; t < M_ / 128; ++t) {
    if (t + 1 < M_ / 128) stage(cur ^ 1, (t + 1) * 128);

    const unsigned char* Kc = Ks[cur];
    const unsigned char* Vc = Vs[cur];

    f32x4 s[8] = {};
    __builtin_amdgcn_s_setprio(1);
    #pragma unroll
    for (int nf = 0; nf < 8; ++nf) {
      const unsigned char* kr = Kc + (nf * 16 + r) * 128;
      ull2 ka = *(const ull2*)(kr + ((g * 32) ^ fx));
      ull2 kb2 = *(const ull2*)(kr + ((g * 32 + 16) ^ fx));
      s[nf] = MFMA8((long long)ka[0], qf[0], s[nf]);
      s[nf] = MFMA8((long long)ka[1], qf[1], s[nf]);
      s[nf] = MFMA8((long long)kb2[0], qf[2], s[nf]);
      s[nf] = MFMA8((long long)kb2[1], qf[3], s[nf]);
    }
    __builtin_amdgcn_s_setprio(0);

    #pragma unroll
    for (int nf = 0; nf < 8; ++nf) {
      float p0 = exp2a(s[nf][0] * escale), p1 = exp2a(s[nf][1] * escale),
            p2 = exp2a(s[nf][2] * escale), p3 = exp2a(s[nf][3] * escale);
      uint32_t w = 0;
      w = (uint32_t)__builtin_amdgcn_cvt_pk_fp8_f32(p0, p1, (int)w, false);
      w = (uint32_t)__builtin_amdgcn_cvt_pk_fp8_f32(p2, p3, (int)w, true);
      int pbase = ((nf & 1) * 2 + (g >> 1)) * 32 + (nf >> 1) * 8 + (g & 1) * 4;
      *(uint32_t*)(Pw + r * 128 + (pbase ^ fx)) = w;
    }

    ull2 pa01 = *(const ull2*)(Pw + r * 128 + ((g * 32) ^ fx));
    ull2 pa23 = *(const ull2*)(Pw + r * 128 + ((g * 32 + 16) ^ fx));
    __builtin_amdgcn_s_setprio(1);
    ol = MFMA8((long long)pa01[0], ONES, ol);
    ol = MFMA8((long long)pa01[1], ONES, ol);
    ol = MFMA8((long long)pa23[0], ONES, ol);
    ol = MFMA8((long long)pa23[1], ONES, ol);
    #pragma unroll
    for (int nf2 = 0; nf2 < 8; ++nf2) {
      const unsigned char* vr = Vc + (nf2 * 16 + r) * 128;
      ull2 va = *(const ull2*)(vr + ((g * 32) ^ fx));
      ull2 vb2 = *(const ull2*)(vr + ((g * 32 + 16) ^ fx));
      o[nf2] = MFMA8((long long)pa01[0], (long long)va[0], o[nf2]);
      o[nf2] = MFMA8((long long)pa01[1], (long long)va[1], o[nf2]);
      o[nf2] = MFMA8((long long)pa23[0], (long long)vb2[0], o[nf2]);
      o[nf2] = MFMA8((long long)pa23[1], (long long)vb2[1], o[nf2]);
    }
    __builtin_amdgcn_s_setprio(0);
    __syncthreads();
    cur ^= 1;
  }

  float invA[4];
  #pragma unroll
  for (int i = 0; i < 4; ++i) invA[i] = 0.03125f / ol[i];
  unsigned short* rr = ret + ((size_t)(b * S_) + s0 + wave * 16) * E_ + h * D_;
  #pragma unroll
  for (int nf2 = 0; nf2 < 8; ++nf2)
    #pragma unroll
    for (int i = 0; i < 4; ++i)
      rr[(size_t)(g * 4 + i) * E_ + nf2 * 16 + r] = f2bf(o[nf2][i] * invA[i]);
}

// ---------------- final: out = query + rmsnorm(retrieved)*w ----------------
__global__ __launch_bounds__(256) void final_kernel(
    const unsigned short* __restrict__ ret, const float* __restrict__ w,
    const float* __restrict__ query, float* __restrict__ out)
{
  const int row = blockIdx.x;
  const int tid = threadIdx.x;
  u16x8 hv = *(const u16x8*)(ret + (size_t)row * E_ + tid * 8);
  float x[8];
  float ss = 0.f;
  #pragma unroll
  for (int j = 0; j < 8; ++j) { x[j] = bf2f(hv[j]); ss += x[j] * x[j]; }
  float tot = block_sum(ss);
  float sc = rsqrtf(tot * (1.0f / E_) + 1e-5f);
  const float* qr = query + (size_t)row * E_ + tid * 8;
  const float* wr = w + tid * 8;
  float o[8];
  #pragma unroll
  for (int j = 0; j < 8; ++j) o[j] = qr[j] + x[j] * sc * wr[j];
  float4* op = (float4*)(out + (size_t)row * E_ + tid * 8);
  op[0] = make_float4(o[0], o[1], o[2], o[3]);
  op[1] = make_float4(o[4], o[5], o[6], o[7]);
}

extern "C" void kernel_launch(void* const* d_in, const int* in_sizes, int n_in,
                              void* d_out, int out_size, void* d_ws, size_t ws_size,
                              hipStream_t stream) {
  const float* query = (const float*)d_in[0];
  const float* sp    = (const float*)d_in[1];
  const float* wq    = (const float*)d_in[2];
  const float* wk    = (const float*)d_in[3];
  const float* wv    = (const float*)d_in[4];
  const float* beta  = (const float*)d_in[5];
  const float* nqw   = (const float*)d_in[6];
  const float* nrw   = (const float*)d_in[7];
  float* out = (float*)d_out;

  char* ws = (char*)d_ws;
  unsigned char*  wqb = (unsigned char*)(ws + 0);                     // 4 MB (fp8)
  unsigned char*  qn  = (unsigned char*)(ws + ((size_t)8 << 20));     // 8 MB (fp8)
  unsigned char*  qb  = (unsigned char*)(ws + ((size_t)24 << 20));    // 8 MB (fp8)
  unsigned char*  kb  = (unsigned char*)(ws + ((size_t)32 << 20));    // 4 MB (fp8)
  unsigned char*  vtb = (unsigned char*)(ws + ((size_t)36 << 20));    // 4 MB (fp8)
  unsigned short* ret = (unsigned short*)(ws + ((size_t)40 << 20));   // 16 MB (bf16)

  f32_to_fp8_kernel<<<2048, 256, 0, stream>>>(wq, wqb, E_ * E_ / 8);
  rmsnorm_q_kernel<<<B_ * S_, 256, 0, stream>>>(query, nqw, qn);
  gemm_qproj<<<(B_ * S_ / 128) * (E_ / 128), 256, 0, stream>>>(
      qn, wqb, qb, B_ * S_, E_, E_);
  proj_kv_kernel<<<dim3(M_ / 64, H_), 256, 0, stream>>>(sp, wk, wv, kb, vtb);
  attn_kernel<<<dim3(S_ / 128, H_, B_), 512, 0, stream>>>(qb, kb, vtb, beta, ret);
  final_kernel<<<B_ * S_, 256, 0, stream>>>(ret, nrw, query, out);
}

// Round 16
// 133.458 us; speedup vs baseline: 2.0768x; 1.0070x over previous
//
#include <hip/hip_runtime.h>
#include <hip/hip_bf16.h>
#include <stdint.h>

typedef __attribute__((ext_vector_type(8))) short bf16x8;
typedef __attribute__((ext_vector_type(4))) float f32x4;
typedef __attribute__((ext_vector_type(8))) unsigned short u16x8;
typedef __attribute__((ext_vector_type(4))) unsigned short u16x4;
typedef __attribute__((ext_vector_type(2))) unsigned long long ull2;

#define B_ 2
#define S_ 2048
#define E_ 2048
#define H_ 16
#define M_ 2048
#define D_ 128

#define MFMA16(a, b, c) __builtin_amdgcn_mfma_f32_16x16x32_bf16(a, b, c, 0, 0, 0)
#define MFMA8(a, b, c) __builtin_amdgcn_mfma_f32_16x16x32_fp8_fp8(a, b, c, 0, 0, 0)

__device__ inline unsigned short f2bf(float f) {
  union { float f; unsigned u; } v; v.f = f;
  unsigned r = v.u + 0x7FFFu + ((v.u >> 16) & 1u);
  return (unsigned short)(r >> 16);
}
__device__ inline float bf2f(unsigned short h) {
  union { unsigned u; float f; } v; v.u = ((unsigned)h) << 16;
  return v.f;
}

// f32 -> e4m3 single byte via HW converter (branch-free; verified r12-r15)
__device__ inline unsigned char f2e8(float f) {
  return (unsigned char)(__builtin_amdgcn_cvt_pk_fp8_f32(f, f, 0, false) & 0xFF);
}
// 4 floats -> 4 packed e4m3 bytes (verified pattern)
__device__ inline uint32_t pk4e8(float a, float b, float c, float d) {
  uint32_t w = 0;
  w = (uint32_t)__builtin_amdgcn_cvt_pk_fp8_f32(a, b, (int)w, false);
  w = (uint32_t)__builtin_amdgcn_cvt_pk_fp8_f32(c, d, (int)w, true);
  return w;
}

// native 2^x
__device__ inline float exp2a(float x) {
  float r;
  asm("v_exp_f32 %0, %1" : "=v"(r) : "v"(x));
  return r;
}

__device__ inline void gload_lds16(const void* g, void* l) {
  __builtin_amdgcn_global_load_lds(
      (__attribute__((address_space(1))) void*)g,
      (__attribute__((address_space(3))) void*)l, 16, 0, 0);
}

__device__ inline bf16x8 pack8(float4 f0, float4 f1) {
  bf16x8 o;
  o[0] = (short)f2bf(f0.x); o[1] = (short)f2bf(f0.y);
  o[2] = (short)f2bf(f0.z); o[3] = (short)f2bf(f0.w);
  o[4] = (short)f2bf(f1.x); o[5] = (short)f2bf(f1.y);
  o[6] = (short)f2bf(f1.z); o[7] = (short)f2bf(f1.w);
  return o;
}

__device__ inline float block_sum(float v) {
  __shared__ float red[4];
  #pragma unroll
  for (int o = 32; o > 0; o >>= 1) v += __shfl_xor(v, o);
  int tid = threadIdx.x;
  if ((tid & 63) == 0) red[tid >> 6] = v;
  __syncthreads();
  return red[0] + red[1] + red[2] + red[3];
}

// pi(col) within a 128-col group: bits[6:5] <-> [4:3]  (col%8 preserved)
__device__ inline int pi_pos(int c) {
  return (c & ~127) | (((c >> 3) & 3) * 32) | (((c >> 5) & 3) * 8) | (c & 7);
}

// ---------------- f32 -> fp8 pi-permuted convert (wq) ----------------
__global__ __launch_bounds__(256) void f32_to_fp8_kernel(
    const float* __restrict__ in, unsigned char* __restrict__ out, int n8)
{
  int i = blockIdx.x * 256 + threadIdx.x;
  if (i >= n8) return;
  const float* p = in + (size_t)i * 8;
  float4 a = *(const float4*)p, b = *(const float4*)(p + 4);
  uint2 pk;
  pk.x = pk4e8(a.x, a.y, a.z, a.w);
  pk.y = pk4e8(b.x, b.y, b.z, b.w);
  size_t flat = (size_t)i * 8;
  int c = (int)(flat & (E_ - 1));        // col within K=2048 row
  *(uint2*)(out + (flat - c) + pi_pos(c)) = pk;
}

// ---------------- RMSNorm(query) -> fp8 qn (pi-permuted) ----------------
__global__ __launch_bounds__(256) void rmsnorm_q_kernel(
    const float* __restrict__ x, const float* __restrict__ w,
    unsigned char* __restrict__ y)
{
  const int row = blockIdx.x;
  const int tid = threadIdx.x;
  const float* xr = x + (size_t)row * E_;
  float4 v0 = ((const float4*)xr)[tid * 2];
  float4 v1 = ((const float4*)xr)[tid * 2 + 1];
  float ss = v0.x*v0.x + v0.y*v0.y + v0.z*v0.z + v0.w*v0.w
           + v1.x*v1.x + v1.y*v1.y + v1.z*v1.z + v1.w*v1.w;
  float tot = block_sum(ss);
  float sc = rsqrtf(tot * (1.0f / E_) + 1e-5f);
  float vals[8] = {v0.x, v0.y, v0.z, v0.w, v1.x, v1.y, v1.z, v1.w};
  const float* wr = w + tid * 8;
  float f[8];
  #pragma unroll
  for (int j = 0; j < 8; ++j) f[j] = vals[j] * sc * wr[j];
  uint2 pk;
  pk.x = pk4e8(f[0], f[1], f[2], f[3]);
  pk.y = pk4e8(f[4], f[5], f[6], f[7]);
  *(uint2*)(y + (size_t)row * E_ + pi_pos(tid * 8)) = pk;
}

// ---------------- GEMM C[M,N] = A[M,K] @ B[N,K]^T (fp8 in, fp8 out) ----------------
__global__ __launch_bounds__(256) void gemm_qproj(
    const unsigned char* __restrict__ A, const unsigned char* __restrict__ B,
    unsigned char* __restrict__ C, int M, int N, int K)
{
  __shared__ __align__(16) unsigned char As[128 * 128];  // 16KB
  __shared__ __align__(16) unsigned char Bs[128 * 128];  // 16KB
  const int nwg = gridDim.x;
  const int cpx = nwg >> 3;
  const int swz = (blockIdx.x & 7) * cpx + (blockIdx.x >> 3);
  const int mt = M >> 7;
  const int bm = (swz % mt) * 128;
  const int bn = (swz / mt) * 128;
  const int tid = threadIdx.x;
  const int wave = tid >> 6, lane = tid & 63;
  const int r = lane & 15, g = lane >> 4;
  const int wm = (wave >> 1) * 64, wn = (wave & 1) * 64;
  const int fx = (r & 7) << 4;

  f32x4 acc[4][4] = {};

  for (int k0 = 0; k0 < K; k0 += 128) {
    #pragma unroll
    for (int c = 0; c < 4; ++c) {
      int chunk = wave * 4 + c;
      int off = chunk * 1024 + lane * 16;
      int row = off >> 7;
      int cb = (off & 127) ^ ((row & 7) << 4);
      gload_lds16(A + (size_t)(bm + row) * K + k0 + cb, (char*)As + chunk * 1024);
      gload_lds16(B + (size_t)(bn + row) * K + k0 + cb, (char*)Bs + chunk * 1024);
    }
    __syncthreads();
    #pragma unroll
    for (int half = 0; half < 2; ++half) {
      ull2 af[4], bf[4];
      #pragma unroll
      for (int m = 0; m < 4; ++m)
        af[m] = *(const ull2*)((const char*)As + (wm + m * 16 + r) * 128
                               + ((g * 32 + half * 16) ^ fx));
      #pragma unroll
      for (int n = 0; n < 4; ++n)
        bf[n] = *(const ull2*)((const char*)Bs + (wn + n * 16 + r) * 128
                               + ((g * 32 + half * 16) ^ fx));
      #pragma unroll
      for (int m = 0; m < 4; ++m)
        #pragma unroll
        for (int n = 0; n < 4; ++n) {
          acc[m][n] = MFMA8((long long)af[m][0], (long long)bf[n][0], acc[m][n]);
          acc[m][n] = MFMA8((long long)af[m][1], (long long)bf[n][1], acc[m][n]);
        }
    }
    __syncthreads();
  }
  #pragma unroll
  for (int m = 0; m < 4; ++m)
    #pragma unroll
    for (int n = 0; n < 4; ++n)
      #pragma unroll
      for (int i = 0; i < 4; ++i) {
        int row = bm + wm + m * 16 + g * 4 + i;
        int col = bn + wn + n * 16 + r;
        C[(size_t)row * N + col] = f2e8(acc[m][n][i]);
      }
}

// ---------------- fused per-head K AND V projections (fp8 out, x32 encode) ----------------
__global__ __launch_bounds__(256, 2) void proj_kv_kernel(
    const float* __restrict__ sp, const float* __restrict__ wk,
    const float* __restrict__ wv,
    unsigned char* __restrict__ kout, unsigned char* __restrict__ vtout)
{
  const int m0 = blockIdx.x * 64;
  const int h = blockIdx.y;
  const int tid = threadIdx.x, wave = tid >> 6, lane = tid & 63;
  const int r = lane & 15, g = lane >> 4;
  const int wm = (wave >> 1) * 32, wn = (wave & 1) * 64;
  const float* spb = sp + ((size_t)h * M_ + m0) * D_;
  f32x4 acck[2][4] = {};
  f32x4 accv[2][4] = {};
  #pragma unroll
  for (int kc = 0; kc < 4; ++kc) {
    bf16x8 a[2], bk[4], bv[4];
    #pragma unroll
    for (int m = 0; m < 2; ++m) {
      const float* p = spb + (size_t)(wm + m * 16 + r) * D_ + kc * 32 + g * 8;
      a[m] = pack8(*(const float4*)p, *(const float4*)(p + 4));
    }
    #pragma unroll
    for (int n = 0; n < 4; ++n) {
      const float* pk = wk + (size_t)(wn + n * 16 + r) * D_ + kc * 32 + g * 8;
      bk[n] = pack8(*(const float4*)pk, *(const float4*)(pk + 4));
      const float* pv = wv + (size_t)(wn + n * 16 + r) * D_ + kc * 32 + g * 8;
      bv[n] = pack8(*(const float4*)pv, *(const float4*)(pv + 4));
    }
    #pragma unroll
    for (int m = 0; m < 2; ++m)
      #pragma unroll
      for (int n = 0; n < 4; ++n) {
        acck[m][n] = MFMA16(a[m], bk[n], acck[m][n]);
        accv[m][n] = MFMA16(a[m], bv[n], accv[m][n]);
      }
  }
  #pragma unroll
  for (int m = 0; m < 2; ++m)
    #pragma unroll
    for (int n = 0; n < 4; ++n)
      #pragma unroll
      for (int i = 0; i < 4; ++i) {
        int d = wn + n * 16 + r;
        kout[((size_t)h * M_ + m0 + wm + m * 16 + g * 4 + i) * D_ + pi_pos(d)]
            = f2e8(acck[m][n][i] * 32.0f);
        int mc = m0 + wm + m * 16 + g * 4 + i;
        int mp = (mc & ~127) | (pi_pos(mc & 127));
        vtout[((size_t)h * D_ + wn + n * 16 + r) * M_ + mp]
            = f2e8(accv[m][n][i] * 32.0f);
      }
}

// ---------------- flash attention over memory slots (fp8, 32 q-rows/wave) ----------------
// grid: (S/128, H, B); block 256 (4 waves x 32 q-rows); KVBLK=128; dbuf 80KB.
// Two q-fragments per wave (rows wave*16+r and +64): each K/V b128 read now
// feeds 4 MFMAs instead of 2 -> per-CU LDS cycles halve (r15's binding pipe).
// Same pi-permuted b128 layout, same per-row arithmetic as r14/r15 (verified).
__global__ __launch_bounds__(256, 2) void attn_kernel(
    const unsigned char* __restrict__ q,    // [B*S][E] e4m3 (pi-permuted cols)
    const unsigned char* __restrict__ kb,   // [H][M][D] e4m3 (x32, pi-permuted d)
    const unsigned char* __restrict__ vtb,  // [H][D][M] e4m3 (x32, pi-permuted m%128)
    const float* __restrict__ beta,
    unsigned short* __restrict__ ret)       // [B*S][E] bf16
{
  __shared__ __align__(16) unsigned char Ks[2][128 * 128];  // 2 x 16KB
  __shared__ __align__(16) unsigned char Vs[2][128 * 128];  // 2 x 16KB
  __shared__ __align__(16) unsigned char Ps[4][32 * 128];   // 16KB
  const int s0 = blockIdx.x * 128;
  const int h = blockIdx.y;
  const int b = blockIdx.z;
  const int tid = threadIdx.x, wave = tid >> 6, lane = tid & 63;
  const int r = lane & 15, g = lane >> 4;
  const int fx = (r & 7) << 4;
  const float escale = beta[h] * (0.08838834764831845f * 1.4426950408889634f / 32.0f);

  // Q fragments: rows wave*16+r (frag0) and +64 (frag1); q is pi-permuted so
  // byte positions match K's LDS layout (contiguous 32B per g).
  long long qf0[4], qf1[4];
  {
    const unsigned char* qr0 =
        q + ((size_t)(b * S_) + s0 + wave * 16 + r) * E_ + h * D_;
    const unsigned char* qr1 = qr0 + (size_t)64 * E_;
    #pragma unroll
    for (int kc = 0; kc < 2; ++kc) {
      ull2 a0 = *(const ull2*)(qr0 + g * 32 + kc * 16);
      ull2 a1 = *(const ull2*)(qr1 + g * 32 + kc * 16);
      qf0[kc * 2] = (long long)a0[0]; qf0[kc * 2 + 1] = (long long)a0[1];
      qf1[kc * 2] = (long long)a1[0]; qf1[kc * 2 + 1] = (long long)a1[1];
    }
  }

  const unsigned char* Kh = kb + (size_t)h * M_ * D_;
  const unsigned char* Vh = vtb + (size_t)h * D_ * M_;
  unsigned char* Pw = Ps[wave];
  const long long ONES = 0x3838383838383838LL;  // e4m3 1.0 x8

  f32x4 o0[8] = {}, o1[8] = {};
  f32x4 ol0 = {}, ol1 = {};

  auto stage = [&](int buf, int m0) {
    #pragma unroll
    for (int c = 0; c < 4; ++c) {
      int chunk = wave * 4 + c;           // 16 x 1KB chunks per 16KB tile
      int off = chunk * 1024 + lane * 16;
      int row = off >> 7;                 // 128B rows
      int cb = (off & 127) ^ ((row & 7) << 4);
      gload_lds16(Kh + (size_t)(m0 + row) * 128 + cb, (char*)Ks[buf] + chunk * 1024);
      gload_lds16(Vh + (size_t)row * M_ + m0 + cb, (char*)Vs[buf] + chunk * 1024);
    }
  };

  stage(0, 0);
  __syncthreads();

  int cur = 0;
  for (int t = 0; t < M_ / 128; ++t) {
    if (t + 1 < M_ / 128) stage(cur ^ 1, (t + 1) * 128);

    const unsigned char* Kc = Ks[cur];
    const unsigned char* Vc = Vs[cur];

    // ---- S^T = K @ Q^T for both q-frags (K reads shared)
    f32x4 sA[8] = {}, sB[8] = {};
    __builtin_amdgcn_s_setprio(1);
    #pragma unroll
    for (int nf = 0; nf < 8; ++nf) {
      const unsigned char* kr = Kc + (nf * 16 + r) * 128;
      ull2 ka = *(const ull2*)(kr + ((g * 32) ^ fx));
      ull2 kb2 = *(const ull2*)(kr + ((g * 32 + 16) ^ fx));
      sA[nf] = MFMA8((long long)ka[0], qf0[0], sA[nf]);
      sB[nf] = MFMA8((long long)ka[0], qf1[0], sB[nf]);
      sA[nf] = MFMA8((long long)ka[1], qf0[1], sA[nf]);
      sB[nf] = MFMA8((long long)ka[1], qf1[1], sB[nf]);
      sA[nf] = MFMA8((long long)kb2[0], qf0[2], sA[nf]);
      sB[nf] = MFMA8((long long)kb2[0], qf1[2], sB[nf]);
      sA[nf] = MFMA8((long long)kb2[1], qf0[3], sA[nf]);
      sB[nf] = MFMA8((long long)kb2[1], qf1[3], sB[nf]);
    }
    __builtin_amdgcn_s_setprio(0);

    // ---- P = 2^(s*escale) for both frags; packed e4m3 b32 writes
    #pragma unroll
    for (int nf = 0; nf < 8; ++nf) {
      int pbase = ((nf & 1) * 2 + (g >> 1)) * 32 + (nf >> 1) * 8 + (g & 1) * 4;
      {
        float p0 = exp2a(sA[nf][0] * escale), p1 = exp2a(sA[nf][1] * escale),
              p2 = exp2a(sA[nf][2] * escale), p3 = exp2a(sA[nf][3] * escale);
        *(uint32_t*)(Pw + r * 128 + (pbase ^ fx)) = pk4e8(p0, p1, p2, p3);
      }
      {
        float p0 = exp2a(sB[nf][0] * escale), p1 = exp2a(sB[nf][1] * escale),
              p2 = exp2a(sB[nf][2] * escale), p3 = exp2a(sB[nf][3] * escale);
        *(uint32_t*)(Pw + (16 + r) * 128 + (pbase ^ fx)) = pk4e8(p0, p1, p2, p3);
      }
    }

    // ---- O += P @ V ; l += P @ ones   (V reads shared across frags)
    ull2 pa01_0 = *(const ull2*)(Pw + r * 128 + ((g * 32) ^ fx));
    ull2 pa23_0 = *(const ull2*)(Pw + r * 128 + ((g * 32 + 16) ^ fx));
    ull2 pa01_1 = *(const ull2*)(Pw + (16 + r) * 128 + ((g * 32) ^ fx));
    ull2 pa23_1 = *(const ull2*)(Pw + (16 + r) * 128 + ((g * 32 + 16) ^ fx));
    __builtin_amdgcn_s_setprio(1);
    ol0 = MFMA8((long long)pa01_0[0], ONES, ol0);
    ol0 = MFMA8((long long)pa01_0[1], ONES, ol0);
    ol0 = MFMA8((long long)pa23_0[0], ONES, ol0);
    ol0 = MFMA8((long long)pa23_0[1], ONES, ol0);
    ol1 = MFMA8((long long)pa01_1[0], ONES, ol1);
    ol1 = MFMA8((long long)pa01_1[1], ONES, ol1);
    ol1 = MFMA8((long long)pa23_1[0], ONES, ol1);
    ol1 = MFMA8((long long)pa23_1[1], ONES, ol1);
    #pragma unroll
    for (int nf2 = 0; nf2 < 8; ++nf2) {
      const unsigned char* vr = Vc + (nf2 * 16 + r) * 128;
      ull2 va = *(const ull2*)(vr + ((g * 32) ^ fx));
      ull2 vb2 = *(const ull2*)(vr + ((g * 32 + 16) ^ fx));
      o0[nf2] = MFMA8((long long)pa01_0[0], (long long)va[0], o0[nf2]);
      o1[nf2] = MFMA8((long long)pa01_1[0], (long long)va[0], o1[nf2]);
      o0[nf2] = MFMA8((long long)pa01_0[1], (long long)va[1], o0[nf2]);
      o1[nf2] = MFMA8((long long)pa01_1[1], (long long)va[1], o1[nf2]);
      o0[nf2] = MFMA8((long long)pa23_0[0], (long long)vb2[0], o0[nf2]);
      o1[nf2] = MFMA8((long long)pa23_1[0], (long long)vb2[0], o1[nf2]);
      o0[nf2] = MFMA8((long long)pa23_0[1], (long long)vb2[1], o0[nf2]);
      o1[nf2] = MFMA8((long long)pa23_1[1], (long long)vb2[1], o1[nf2]);
    }
    __builtin_amdgcn_s_setprio(0);
    __syncthreads();
    cur ^= 1;
  }

  // ---- epilogue: retrieved = (O_enc / l) / 32 ; no cross-lane needed
  {
    float inv[4];
    #pragma unroll
    for (int i = 0; i < 4; ++i) inv[i] = 0.03125f / ol0[i];
    unsigned short* rr = ret + ((size_t)(b * S_) + s0 + wave * 16) * E_ + h * D_;
    #pragma unroll
    for (int nf2 = 0; nf2 < 8; ++nf2)
      #pragma unroll
      for (int i = 0; i < 4; ++i)
        rr[(size_t)(g * 4 + i) * E_ + nf2 * 16 + r] = f2bf(o0[nf2][i] * inv[i]);
  }
  {
    float inv[4];
    #pragma unroll
    for (int i = 0; i < 4; ++i) inv[i] = 0.03125f / ol1[i];
    unsigned short* rr = ret + ((size_t)(b * S_) + s0 + 64 + wave * 16) * E_ + h * D_;
    #pragma unroll
    for (int nf2 = 0; nf2 < 8; ++nf2)
      #pragma unroll
      for (int i = 0; i < 4; ++i)
        rr[(size_t)(g * 4 + i) * E_ + nf2 * 16 + r] = f2bf(o1[nf2][i] * inv[i]);
  }
}

// ---------------- final: out = query + rmsnorm(retrieved)*w ----------------
__global__ __launch_bounds__(256) void final_kernel(
    const unsigned short* __restrict__ ret, const float* __restrict__ w,
    const float* __restrict__ query, float* __restrict__ out)
{
  const int row = blockIdx.x;
  const int tid = threadIdx.x;
  u16x8 hv = *(const u16x8*)(ret + (size_t)row * E_ + tid * 8);
  float x[8];
  float ss = 0.f;
  #pragma unroll
  for (int j = 0; j < 8; ++j) { x[j] = bf2f(hv[j]); ss += x[j] * x[j]; }
  float tot = block_sum(ss);
  float sc = rsqrtf(tot * (1.0f / E_) + 1e-5f);
  const float* qr = query + (size_t)row * E_ + tid * 8;
  const float* wr = w + tid * 8;
  float o[8];
  #pragma unroll
  for (int j = 0; j < 8; ++j) o[j] = qr[j] + x[j] * sc * wr[j];
  float4* op = (float4*)(out + (size_t)row * E_ + tid * 8);
  op[0] = make_float4(o[0], o[1], o[2], o[3]);
  op[1] = make_float4(o[4], o[5], o[6], o[7]);
}

extern "C" void kernel_launch(void* const* d_in, const int* in_sizes, int n_in,
                              void* d_out, int out_size, void* d_ws, size_t ws_size,
                              hipStream_t stream) {
  const float* query = (const float*)d_in[0];
  const float* sp    = (const float*)d_in[1];
  const float* wq    = (const float*)d_in[2];
  const float* wk    = (const float*)d_in[3];
  const float* wv    = (const float*)d_in[4];
  const float* beta  = (const float*)d_in[5];
  const float* nqw   = (const float*)d_in[6];
  const float* nrw   = (const float*)d_in[7];
  float* out = (float*)d_out;

  char* ws = (char*)d_ws;
  unsigned char*  wqb = (unsigned char*)(ws + 0);                     // 4 MB (fp8)
  unsigned char*  qn  = (unsigned char*)(ws + ((size_t)8 << 20));     // 8 MB (fp8)
  unsigned char*  qb  = (unsigned char*)(ws + ((size_t)24 << 20));    // 8 MB (fp8)
  unsigned char*  kb  = (unsigned char*)(ws + ((size_t)32 << 20));    // 4 MB (fp8)
  unsigned char*  vtb = (unsigned char*)(ws + ((size_t)36 << 20));    // 4 MB (fp8)
  unsigned short* ret = (unsigned short*)(ws + ((size_t)40 << 20));   // 16 MB (bf16)

  f32_to_fp8_kernel<<<2048, 256, 0, stream>>>(wq, wqb, E_ * E_ / 8);
  rmsnorm_q_kernel<<<B_ * S_, 256, 0, stream>>>(query, nqw, qn);
  gemm_qproj<<<(B_ * S_ / 128) * (E_ / 128), 256, 0, stream>>>(
      qn, wqb, qb, B_ * S_, E_, E_);
  proj_kv_kernel<<<dim3(M_ / 64, H_), 256, 0, stream>>>(sp, wk, wv, kb, vtb);
  attn_kernel<<<dim3(S_ / 128, H_, B_), 256, 0, stream>>>(qb, kb, vtb, beta, ret);
  final_kernel<<<B_ * S_, 256, 0, stream>>>(ret, nrw, query, out);
}